// Round 6
// baseline (474.363 us; speedup 1.0000x reference)
//
#include <hip/hip_runtime.h>

typedef __attribute__((ext_vector_type(8))) __bf16 bf16x8;
typedef __attribute__((ext_vector_type(4))) __bf16 bf16x4;
typedef __attribute__((ext_vector_type(4))) float floatx4;
typedef void __attribute__((address_space(3))) lds_void_t;
typedef const void __attribute__((address_space(1))) gbl_void_t;

#define D_MODEL 1024
#define SEQ     2048
#define BATCH   2
#define NH      16
#define DK      64
#define DFF     4096
#define NTOK    (BATCH * SEQ)   // 4096
#define QKVS    3072            // fused qkv row stride

#if __has_builtin(__builtin_amdgcn_exp2f)
#define EXP2(x) __builtin_amdgcn_exp2f(x)
#else
#define EXP2(x) exp2f(x)
#endif

__device__ __forceinline__ float gelu_exact(float x) {
    return 0.5f * x * (1.0f + erff(x * 0.70710678118654752f));
}

// ---------------- fp32 -> bf16 weight cast, 8 elems/thread --------------------------
__global__ __launch_bounds__(256) void cast_f32_bf16(const float* __restrict__ src,
                                                     __bf16* __restrict__ dst, int n) {
    int i = (blockIdx.x * 256 + threadIdx.x) * 8;
    if (i >= n) return;
    floatx4 a = *(const floatx4*)(src + i);
    floatx4 b = *(const floatx4*)(src + i + 4);
    bf16x8 o;
    for (int j = 0; j < 4; ++j) { o[j] = (__bf16)a[j]; o[4 + j] = (__bf16)b[j]; }
    *(bf16x8*)(dst + i) = o;
}

// ---------------- LayerNorm: one wave per row of 1024; fp32 in, bf16 out ------------
__global__ __launch_bounds__(64) void ln_kernel(const float* __restrict__ x,
                                                const float* __restrict__ g,
                                                const float* __restrict__ b,
                                                __bf16* __restrict__ out) {
    int row = blockIdx.x, lane = threadIdx.x, base = lane * 16;
    const float* xr = x + (size_t)row * D_MODEL + base;
    float v[16];
    for (int j = 0; j < 4; ++j) {
        floatx4 a = *(const floatx4*)(xr + 4 * j);
        for (int i = 0; i < 4; ++i) v[4 * j + i] = a[i];
    }
    float s = 0.f, sq = 0.f;
    for (int i = 0; i < 16; ++i) { s += v[i]; sq += v[i] * v[i]; }
    for (int o = 1; o < 64; o <<= 1) { s += __shfl_xor(s, o); sq += __shfl_xor(sq, o); }
    float mu = s * (1.0f / D_MODEL);
    float var = sq * (1.0f / D_MODEL) - mu * mu;
    float rstd = rsqrtf(fmaxf(var, 0.f) + 1e-5f);

    const floatx4* gp = (const floatx4*)(g + base);
    const floatx4* bp = (const floatx4*)(b + base);
    bf16x8 o0, o1;
    for (int j = 0; j < 2; ++j) {
        floatx4 gv0 = gp[2 * j], gv1 = gp[2 * j + 1];
        floatx4 bv0 = bp[2 * j], bv1 = bp[2 * j + 1];
        for (int i = 0; i < 4; ++i) {
            float r0 = (v[8 * j + i] - mu) * rstd * gv0[i] + bv0[i];
            float r1 = (v[8 * j + 4 + i] - mu) * rstd * gv1[i] + bv1[i];
            if (j == 0) { o0[i] = (__bf16)r0; o0[4 + i] = (__bf16)r1; }
            else        { o1[i] = (__bf16)r0; o1[4 + i] = (__bf16)r1; }
        }
    }
    bf16x8* op = (bf16x8*)(out + (size_t)row * D_MODEL + base);
    op[0] = o0; op[1] = o1;
}

// ---------------- GEMM: C = A@W^T + bias (+gelu) (+res) -----------------------------
// 128x128 tile, BK=32, 4 waves. Counted-vmcnt 3-buffer pipeline (T4/m218 pattern):
// tiles t+1,t+2 in flight; per step each wave does s_waitcnt vmcnt(4) (waits ONLY its
// own 4 stage-t loads; newer 4 stay in flight across the barrier), then raw s_barrier
// (=> all waves' tile-t writes landed), then stages t+2 and computes t. vmcnt never
// drains to 0 in the loop (only the peeled last step).
// LDS is FRAGMENT-ORDERED: 8 blocks of 1024B per matrix-tile, block = one MFMA
// fragment set, read at base+lane*16 (conflict-free, imm offsets). global_load_lds's
// per-lane SOURCE provides the permutation:
//   block blk=(grp,i): lane l <- M[row=grp*64+i*16+(l&15)][k0+(l>>4)*8 ..+8)
// KSPLIT>1: blockIdx.z takes a K-slice, raw fp32 partial; reduce_k2 finishes.
template <typename OutT, bool GELU, bool TRIBIAS, int KSPLIT>
__global__ __launch_bounds__(256) void gemm_bt(const __bf16* __restrict__ A,
                                               const __bf16* __restrict__ W,
                                               const float* __restrict__ bias0,
                                               const float* __restrict__ bias1,
                                               const float* __restrict__ bias2,
                                               const float* __restrict__ res,
                                               OutT* out, float* part1,
                                               int M, int N, int K) {
    __shared__ __bf16 AsF[3][4096];   // 3 buffers x 8 fragment-blocks x 512 elems
    __shared__ __bf16 WsF[3][4096];

    int m0 = blockIdx.y * 128, n0 = blockIdx.x * 128;
    int t = threadIdx.x;
    int lane = t & 63, wave = t >> 6;
    int wm = (wave >> 1) * 64, wn = (wave & 1) * 64;
    int fr = lane & 15, quad = lane >> 4;
    int scol = quad * 8;              // col within 32-col fragment (staging source)

    int Ks = K / KSPLIT;
    int kbeg = (KSPLIT > 1) ? blockIdx.z * Ks : 0;

    floatx4 acc[4][4] = {};

    const __bf16* Abase = A + kbeg;
    const __bf16* Wbase = W + kbeg;

    // stage tile k0 into buffer buf: 2 passes x (1 A-load + 1 W-load) per wave
    auto stage = [&](int buf, int k0) {
#pragma unroll
        for (int p = 0; p < 2; ++p) {
            int blk = p * 4 + wave;
            int row = (blk >> 2) * 64 + (blk & 3) * 16 + fr;
            __builtin_amdgcn_global_load_lds(
                (gbl_void_t*)(Abase + (size_t)(m0 + row) * K + k0 + scol),
                (lds_void_t*)&AsF[buf][blk * 512], 16, 0, 0);
            __builtin_amdgcn_global_load_lds(
                (gbl_void_t*)(Wbase + (size_t)(n0 + row) * K + k0 + scol),
                (lds_void_t*)&WsF[buf][blk * 512], 16, 0, 0);
        }
    };

    auto compute = [&](int buf) {
        bf16x8 af[4], wf[4];
#pragma unroll
        for (int i = 0; i < 4; ++i)
            af[i] = *(const bf16x8*)&AsF[buf][((wave >> 1) * 4 + i) * 512 + lane * 8];
#pragma unroll
        for (int i = 0; i < 4; ++i)
            wf[i] = *(const bf16x8*)&WsF[buf][((wave & 1) * 4 + i) * 512 + lane * 8];
#pragma unroll
        for (int mi = 0; mi < 4; ++mi)
#pragma unroll
            for (int ni = 0; ni < 4; ++ni)
                acc[mi][ni] = __builtin_amdgcn_mfma_f32_16x16x32_bf16(af[mi], wf[ni], acc[mi][ni], 0, 0, 0);
    };

    int nsteps = Ks / 32;
    stage(0, 0);
    stage(1, 32);
    int cur = 0;
    for (int s = 0; s < nsteps - 1; ++s) {
        asm volatile("s_waitcnt vmcnt(4)" ::: "memory");   // own tile-s loads landed
        __builtin_amdgcn_s_barrier();                      // everyone's landed
        __builtin_amdgcn_sched_barrier(0);
        if (s + 2 < nsteps) {
            int b2 = cur + 2; if (b2 >= 3) b2 -= 3;
            stage(b2, (s + 2) * 32);
        }
        compute(cur);
        cur = (cur == 2) ? 0 : cur + 1;
    }
    asm volatile("s_waitcnt vmcnt(0)" ::: "memory");
    __builtin_amdgcn_s_barrier();
    __builtin_amdgcn_sched_barrier(0);
    compute(cur);

    if (KSPLIT > 1) {
        float* pb = (blockIdx.z == 0) ? (float*)out : part1;
#pragma unroll
        for (int ni = 0; ni < 4; ++ni) {
            int col = n0 + wn + ni * 16 + fr;
#pragma unroll
            for (int mi = 0; mi < 4; ++mi)
#pragma unroll
                for (int r = 0; r < 4; ++r) {
                    int row = m0 + wm + mi * 16 + quad * 4 + r;
                    pb[(size_t)row * N + col] = acc[mi][ni][r];
                }
        }
    } else {
#pragma unroll
        for (int ni = 0; ni < 4; ++ni) {
            int col = n0 + wn + ni * 16 + fr;
            const float* bp = bias0;
            int bcol = col;
            if (TRIBIAS) { bp = col < 1024 ? bias0 : (col < 2048 ? bias1 : bias2); bcol = col & 1023; }
            float bv = bp[bcol];
#pragma unroll
            for (int mi = 0; mi < 4; ++mi) {
#pragma unroll
                for (int r = 0; r < 4; ++r) {
                    int row = m0 + wm + mi * 16 + quad * 4 + r;
                    float v = acc[mi][ni][r] + bv;
                    if (GELU) v = gelu_exact(v);
                    if (res) v += res[(size_t)row * N + col];
                    out[(size_t)row * N + col] = (OutT)v;
                }
            }
        }
    }
}

// ---------------- split-K reduce: out = p0 + p1 + res + bias (N=1024 pow2) ----------
__global__ __launch_bounds__(256) void reduce_k2(const float* __restrict__ p0,
                                                 const float* p1,
                                                 const float* __restrict__ res,
                                                 const float* __restrict__ bias,
                                                 float* out) {
    int i = (blockIdx.x * 256 + threadIdx.x) * 4;
    floatx4 a = *(const floatx4*)(p0 + i);
    floatx4 b = *(const floatx4*)(p1 + i);
    floatx4 r = *(const floatx4*)(res + i);
    floatx4 bv = *(const floatx4*)(bias + (i & 1023));
    floatx4 o;
#pragma unroll
    for (int j = 0; j < 4; ++j) o[j] = a[j] + b[j] + r[j] + bv[j];
    *(floatx4*)(out + i) = o;
}

// ---------------- V transpose: qkv v-part [b][s][2048+h*64+d] -> vt[b][h][d][s] -----
__global__ __launch_bounds__(256) void transpose_v(const __bf16* __restrict__ qkv,
                                                   __bf16* __restrict__ vt) {
    __shared__ __bf16 tile[64][72];
    int b = blockIdx.z, h = blockIdx.y, s0 = blockIdx.x * 64;
    int t = threadIdx.x;
    int dl = (t & 7) * 8, sl = t >> 3;
    for (int p = 0; p < 2; ++p) {
        int s = sl + p * 32;
        bf16x8 val = *(const bf16x8*)(qkv + (size_t)(b * SEQ + s0 + s) * QKVS + 2048 + h * DK + dl);
        *(bf16x8*)&tile[s][dl] = val;
    }
    __syncthreads();
    int sl2 = (t & 7) * 8, d = t >> 3;
    for (int p = 0; p < 2; ++p) {
        int dd = d + p * 32;
        bf16x8 val;
        for (int j = 0; j < 8; ++j) val[j] = tile[sl2 + j][dd];
        *(bf16x8*)(vt + ((size_t)(b * NH + h) * DK + dd) * SEQ + s0 + sl2) = val;
    }
}

// ---------------- Flash attention, 32 queries/wave, fragment-ordered LDS K/V --------
// (unchanged from round 5 -- left the top-5)
__global__ __launch_bounds__(256, 2) void attn_kernel(const __bf16* __restrict__ qkv,
                                                      const __bf16* __restrict__ vt,
                                                      __bf16* __restrict__ ctx) {
    __shared__ __bf16 Klds[8192];        // 16 blocks x 1024B, block (f,half)=f*2+half
    __shared__ __bf16 Vlds[8192];        // 16 blocks x 1024B, block (c,ti)=c*4+ti
    __shared__ __bf16 Plds[4][32][136];  // [wave][query 32][128 keys + 8 pad]
    int b = blockIdx.z, h = blockIdx.y;
    int wave = threadIdx.x >> 6, lane = threadIdx.x & 63;
    int q0 = blockIdx.x * 128 + wave * 32;
    int fr = lane & 15, quad = lane >> 4;
    const float sc2 = 0.18033688011112042f;   // (1/sqrt(64)) * log2(e)

    const __bf16* qp0 = qkv + (size_t)(b * SEQ + q0 + fr) * QKVS + h * DK + quad * 8;
    const __bf16* qp1 = qp0 + (size_t)16 * QKVS;
    bf16x8 qA0 = *(const bf16x8*)qp0, qB0 = *(const bf16x8*)(qp0 + 32);
    bf16x8 qA1 = *(const bf16x8*)qp1, qB1 = *(const bf16x8*)(qp1 + 32);

    const __bf16* kg = qkv + (size_t)b * SEQ * QKVS + 1024 + h * DK;  // + key*QKVS + d
    const __bf16* vg = vt + (size_t)(b * NH + h) * DK * SEQ;          // + d*SEQ + key

    floatx4 o[8] = {};   // [hh*4+ti]: row=query hh*16+quad*4+r, col=d ti*16+fr
    float m0q = -1e30f, l0q = 0.f, m1q = -1e30f, l1q = 0.f;

    auto stage_tile = [&](int k0) {
#pragma unroll
        for (int p = 0; p < 4; ++p) {
            int bid = wave * 4 + p;
            int f = bid >> 1, half = bid & 1;
            __builtin_amdgcn_global_load_lds(
                (gbl_void_t*)(kg + (size_t)(k0 + f * 16 + fr) * QKVS + quad * 8 + half * 32),
                (lds_void_t*)&Klds[bid * 512], 16, 0, 0);
            int c = bid >> 2, ti = bid & 3;
            __builtin_amdgcn_global_load_lds(
                (gbl_void_t*)(vg + (size_t)(ti * 16 + fr) * SEQ + k0 + c * 32 + quad * 8),
                (lds_void_t*)&Vlds[bid * 512], 16, 0, 0);
        }
    };

    stage_tile(0);
    __syncthreads();   // drains vmcnt -> tile 0 in LDS

    for (int k0 = 0; k0 < SEQ; k0 += 128) {
        const __bf16* Kb = Klds + lane * 8;
        const __bf16* Vb = Vlds + lane * 8;
        bf16x8 kA[8], kB[8];
#pragma unroll
        for (int f = 0; f < 8; ++f) {
            kA[f] = *(const bf16x8*)(Kb + (f * 2 + 0) * 512);
            kB[f] = *(const bf16x8*)(Kb + (f * 2 + 1) * 512);
        }

        // ---- QK^T half 0 ----
        floatx4 s[8];
#pragma unroll
        for (int f = 0; f < 8; ++f) {
            floatx4 z = {0.f, 0.f, 0.f, 0.f};
            z = __builtin_amdgcn_mfma_f32_16x16x32_bf16(kA[f], qA0, z, 0, 0, 0);
            s[f] = __builtin_amdgcn_mfma_f32_16x16x32_bf16(kB[f], qB0, z, 0, 0, 0);
        }
        // ---- softmax half 0 ----
        {
            float fm[8];
#pragma unroll
            for (int f = 0; f < 8; ++f)
                fm[f] = fmaxf(fmaxf(s[f][0], s[f][1]), fmaxf(s[f][2], s[f][3]));
            float mx = fmaxf(fmaxf(fmaxf(fm[0], fm[1]), fmaxf(fm[2], fm[3])),
                             fmaxf(fmaxf(fm[4], fm[5]), fmaxf(fm[6], fm[7])));
            float mx2 = mx * sc2;
            mx2 = fmaxf(mx2, __shfl_xor(mx2, 16));
            mx2 = fmaxf(mx2, __shfl_xor(mx2, 32));
            float mn = fmaxf(m0q, mx2);
            float alpha = EXP2(m0q - mn);
            m0q = mn;
            float r0 = 0.f, r1 = 0.f, r2 = 0.f, r3 = 0.f;
#pragma unroll
            for (int f = 0; f < 8; ++f) {
                bf16x4 pk;
                float p0 = EXP2(fmaf(s[f][0], sc2, -mn));
                float p1 = EXP2(fmaf(s[f][1], sc2, -mn));
                float p2 = EXP2(fmaf(s[f][2], sc2, -mn));
                float p3 = EXP2(fmaf(s[f][3], sc2, -mn));
                r0 += p0; r1 += p1; r2 += p2; r3 += p3;
                pk[0] = (__bf16)p0; pk[1] = (__bf16)p1; pk[2] = (__bf16)p2; pk[3] = (__bf16)p3;
                *(bf16x4*)&Plds[wave][fr][f * 16 + quad * 4] = pk;
            }
            float rs = (r0 + r1) + (r2 + r3);
            rs += __shfl_xor(rs, 16);
            rs += __shfl_xor(rs, 32);
            l0q = l0q * alpha + rs;
            float aB[4];
#pragma unroll
            for (int r = 0; r < 4; ++r) aB[r] = __shfl(alpha, quad * 4 + r);
#pragma unroll
            for (int ti = 0; ti < 4; ++ti)
#pragma unroll
                for (int r = 0; r < 4; ++r) o[ti][r] *= aB[r];
        }

        // ---- QK^T half 1 ----
        floatx4 s1[8];
#pragma unroll
        for (int f = 0; f < 8; ++f) {
            floatx4 z = {0.f, 0.f, 0.f, 0.f};
            z = __builtin_amdgcn_mfma_f32_16x16x32_bf16(kA[f], qA1, z, 0, 0, 0);
            s1[f] = __builtin_amdgcn_mfma_f32_16x16x32_bf16(kB[f], qB1, z, 0, 0, 0);
        }

        // ---- V fragment reads (K regs free) ----
        bf16x8 vf[4][4];
#pragma unroll
        for (int c = 0; c < 4; ++c)
#pragma unroll
            for (int ti = 0; ti < 4; ++ti)
                vf[c][ti] = *(const bf16x8*)(Vb + (c * 4 + ti) * 512);

        __syncthreads();   // all waves done reading K/V LDS
        if (k0 + 128 < SEQ) stage_tile(k0 + 128);   // loads fly under softmax h1 + PV

        // ---- softmax half 1 ----
        {
            float fm[8];
#pragma unroll
            for (int f = 0; f < 8; ++f)
                fm[f] = fmaxf(fmaxf(s1[f][0], s1[f][1]), fmaxf(s1[f][2], s1[f][3]));
            float mx = fmaxf(fmaxf(fmaxf(fm[0], fm[1]), fmaxf(fm[2], fm[3])),
                             fmaxf(fmaxf(fm[4], fm[5]), fmaxf(fm[6], fm[7])));
            float mx2 = mx * sc2;
            mx2 = fmaxf(mx2, __shfl_xor(mx2, 16));
            mx2 = fmaxf(mx2, __shfl_xor(mx2, 32));
            float mn = fmaxf(m1q, mx2);
            float alpha = EXP2(m1q - mn);
            m1q = mn;
            float r0 = 0.f, r1 = 0.f, r2 = 0.f, r3 = 0.f;
#pragma unroll
            for (int f = 0; f < 8; ++f) {
                bf16x4 pk;
                float p0 = EXP2(fmaf(s1[f][0], sc2, -mn));
                float p1 = EXP2(fmaf(s1[f][1], sc2, -mn));
                float p2 = EXP2(fmaf(s1[f][2], sc2, -mn));
                float p3 = EXP2(fmaf(s1[f][3], sc2, -mn));
                r0 += p0; r1 += p1; r2 += p2; r3 += p3;
                pk[0] = (__bf16)p0; pk[1] = (__bf16)p1; pk[2] = (__bf16)p2; pk[3] = (__bf16)p3;
                *(bf16x4*)&Plds[wave][16 + fr][f * 16 + quad * 4] = pk;
            }
            float rs = (r0 + r1) + (r2 + r3);
            rs += __shfl_xor(rs, 16);
            rs += __shfl_xor(rs, 32);
            l1q = l1q * alpha + rs;
            float aB[4];
#pragma unroll
            for (int r = 0; r < 4; ++r) aB[r] = __shfl(alpha, quad * 4 + r);
#pragma unroll
            for (int ti = 0; ti < 4; ++ti)
#pragma unroll
                for (int r = 0; r < 4; ++r) o[4 + ti][r] *= aB[r];
        }
        __threadfence_block();   // order wave-private Plds writes -> cross-lane reads

        // ---- PV both halves ----
        bf16x8 pa0[4], pa1[4];
#pragma unroll
        for (int c = 0; c < 4; ++c) {
            pa0[c] = *(const bf16x8*)&Plds[wave][fr][c * 32 + quad * 8];
            pa1[c] = *(const bf16x8*)&Plds[wave][16 + fr][c * 32 + quad * 8];
        }
#pragma unroll
        for (int c = 0; c < 4; ++c)
#pragma unroll
            for (int ti = 0; ti < 4; ++ti) {
                o[ti]     = __builtin_amdgcn_mfma_f32_16x16x32_bf16(pa0[c], vf[c][ti], o[ti], 0, 0, 0);
                o[4 + ti] = __builtin_amdgcn_mfma_f32_16x16x32_bf16(pa1[c], vf[c][ti], o[4 + ti], 0, 0, 0);
            }
        __threadfence_block();   // P reads done before next iteration's writes

        __syncthreads();   // drains vmcnt -> staged tile t+1 ready in LDS
    }
    float lB0[4], lB1[4];
#pragma unroll
    for (int r = 0; r < 4; ++r) {
        lB0[r] = __shfl(l0q, quad * 4 + r);
        lB1[r] = __shfl(l1q, quad * 4 + r);
    }
#pragma unroll
    for (int ti = 0; ti < 4; ++ti)
#pragma unroll
        for (int r = 0; r < 4; ++r) {
            ctx[(size_t)(b * SEQ + q0 + quad * 4 + r) * D_MODEL + h * DK + ti * 16 + fr] =
                (__bf16)(o[ti][r] / lB0[r]);
            ctx[(size_t)(b * SEQ + q0 + 16 + quad * 4 + r) * D_MODEL + h * DK + ti * 16 + fr] =
                (__bf16)(o[4 + ti][r] / lB1[r]);
        }
}

// -----------------------------------------------------------------------------------
// Workspace 72 MiB:
//   [0,6M):   wqkvB    [6,8M): woB    [8,16M): w1B    [16,24M): w2B
//   [24,40M): h1 -> x1 fp32 trunk
//   [40,64M): qkv      [64,72M): vt
//   AO split-K partials:  [40,56M) + [56,72M)  (qkv/vt dead after attn)
//   ffh = [40,72M) after AO reduce
//   FF2 split-K partials: [0,16M) (wqkvB/woB/w1B dead) + d_out (h2 dead)
//   d_out:    ctx -> h2 -> FF2 partial1 -> final out
extern "C" void kernel_launch(void* const* d_in, const int* in_sizes, int n_in,
                              void* d_out, int out_size, void* d_ws, size_t ws_size,
                              hipStream_t stream) {
    const float* x   = (const float*)d_in[0];
    const float* wq  = (const float*)d_in[1];
    const float* bq  = (const float*)d_in[2];
    const float* wk  = (const float*)d_in[3];
    const float* bk  = (const float*)d_in[4];
    const float* wv  = (const float*)d_in[5];
    const float* bv  = (const float*)d_in[6];
    const float* wo  = (const float*)d_in[7];
    const float* bo  = (const float*)d_in[8];
    const float* w1  = (const float*)d_in[9];
    const float* b1  = (const float*)d_in[10];
    const float* w2  = (const float*)d_in[11];
    const float* b2  = (const float*)d_in[12];
    const float* g1  = (const float*)d_in[13];
    const float* be1 = (const float*)d_in[14];
    const float* g2  = (const float*)d_in[15];
    const float* be2 = (const float*)d_in[16];
    float* out = (float*)d_out;

    char* ws = (char*)d_ws;
    const size_t MB = 1024 * 1024;
    __bf16* wqkvB = (__bf16*)(ws);                 // [0,6M)
    __bf16* woB   = (__bf16*)(ws + 6 * MB);
    __bf16* w1B   = (__bf16*)(ws + 8 * MB);
    __bf16* w2B   = (__bf16*)(ws + 16 * MB);
    __bf16* h1    = (__bf16*)(ws + 24 * MB);       // dead after qkv-gemm
    float*  x1    = (float*)(ws + 24 * MB);        // fp32 trunk [24,40M)
    __bf16* qkv   = (__bf16*)(ws + 40 * MB);       // [40,64M)
    __bf16* vt    = (__bf16*)(ws + 64 * MB);       // [64,72M)
    __bf16* ffh   = (__bf16*)(ws + 40 * MB);       // [40,72M) after qkv+vt die
    float*  pA0   = (float*)(ws + 40 * MB);        // AO partial z=0
    float*  pA1   = (float*)(ws + 56 * MB);        // AO partial z=1
    float*  pF0   = (float*)(ws);                  // FF2 partial z=0 [0,16M)
    __bf16* ctx   = (__bf16*)d_out;                // d_out scratch [0,8M)
    __bf16* h2    = (__bf16*)d_out;                // d_out scratch (after ctx dies)

    const int NDD = D_MODEL * D_MODEL;   // 1M
    const int NDF = D_MODEL * DFF;       // 4M
    cast_f32_bf16<<<NDD / 2048, 256, 0, stream>>>(wq, wqkvB, NDD);
    cast_f32_bf16<<<NDD / 2048, 256, 0, stream>>>(wk, wqkvB + NDD, NDD);
    cast_f32_bf16<<<NDD / 2048, 256, 0, stream>>>(wv, wqkvB + 2 * NDD, NDD);
    cast_f32_bf16<<<NDD / 2048, 256, 0, stream>>>(wo, woB, NDD);
    cast_f32_bf16<<<NDF / 2048, 256, 0, stream>>>(w1, w1B, NDF);
    cast_f32_bf16<<<NDF / 2048, 256, 0, stream>>>(w2, w2B, NDF);

    dim3 gQKV(QKVS / 128, NTOK / 128);       // (24, 32) = 768 blocks
    dim3 gDz(D_MODEL / 128, NTOK / 128, 2);  // (8, 32, 2) = 512 blocks, split-K=2
    dim3 gF(DFF / 128, NTOK / 128);          // (32, 32) = 1024 blocks
    dim3 gTr(SEQ / 64, NH, BATCH);           // (32, 16, 2) transpose_v
    dim3 gAttn(SEQ / 128, NH, BATCH);        // (16, 16, 2) = 512 blocks, 2/CU
    int gRed = NTOK * D_MODEL / (256 * 4);   // 4096 blocks

    // 1. h1 = LN(x, g1, be1)
    ln_kernel<<<NTOK, 64, 0, stream>>>(x, g1, be1, h1);
    // 2. qkv = h1 @ [wq;wk;wv]^T + [bq;bk;bv]   (fused, N=3072)
    gemm_bt<__bf16, false, true, 1><<<gQKV, 256, 0, stream>>>(h1, wqkvB, bq, bk, bv, nullptr, qkv, nullptr, NTOK, QKVS, D_MODEL);
    // 3. vt = transpose(v) per head
    transpose_v<<<gTr, 256, 0, stream>>>(qkv, vt);
    // 4. ctx = softmax(q k^T / sqrt(dk)) v   (writes d_out)
    attn_kernel<<<gAttn, 256, 0, stream>>>(qkv, vt, ctx);
    // 5. x1 = x + ctx @ wo^T + bo   (split-K=2: partials over dead qkv/vt, then reduce)
    gemm_bt<float, false, false, 2><<<gDz, 256, 0, stream>>>(ctx, woB, nullptr, nullptr, nullptr, nullptr, pA0, pA1, NTOK, D_MODEL, D_MODEL);
    reduce_k2<<<gRed, 256, 0, stream>>>(pA0, pA1, x, bo, x1);
    // 6. h2 = LN(x1, g2, be2)   (d_out scratch)
    ln_kernel<<<NTOK, 64, 0, stream>>>(x1, g2, be2, h2);
    // 7. ffh = gelu(h2 @ w1^T + b1)   (full 32 MiB over qkv+vt)
    gemm_bt<__bf16, true, false, 1><<<gF, 256, 0, stream>>>(h2, w1B, b1, b1, b1, nullptr, ffh, nullptr, NTOK, DFF, D_MODEL);
    // 8. out = x1 + ffh @ w2^T + b2   (split-K=2: p0=[0,16M), p1=d_out, reduce in place)
    gemm_bt<float, false, false, 2><<<gDz, 256, 0, stream>>>(ffh, w2B, nullptr, nullptr, nullptr, nullptr, pF0, (float*)d_out, NTOK, D_MODEL, DFF);
    reduce_k2<<<gRed, 256, 0, stream>>>(pF0, (float*)d_out, x1, b2, out);
}

// Round 7
// 471.772 us; speedup vs baseline: 1.0055x; 1.0055x over previous
//
#include <hip/hip_runtime.h>

typedef __attribute__((ext_vector_type(8))) __bf16 bf16x8;
typedef __attribute__((ext_vector_type(4))) __bf16 bf16x4;
typedef __attribute__((ext_vector_type(4))) float floatx4;
typedef void __attribute__((address_space(3))) lds_void_t;
typedef const void __attribute__((address_space(1))) gbl_void_t;

#define D_MODEL 1024
#define SEQ     2048
#define BATCH   2
#define NH      16
#define DK      64
#define DFF     4096
#define NTOK    (BATCH * SEQ)   // 4096
#define QKVS    3072            // fused qkv row stride

#if __has_builtin(__builtin_amdgcn_exp2f)
#define EXP2(x) __builtin_amdgcn_exp2f(x)
#else
#define EXP2(x) exp2f(x)
#endif

__device__ __forceinline__ float gelu_exact(float x) {
    return 0.5f * x * (1.0f + erff(x * 0.70710678118654752f));
}

// ---------------- fp32 -> bf16 weight cast, 8 elems/thread --------------------------
__global__ __launch_bounds__(256) void cast_f32_bf16(const float* __restrict__ src,
                                                     __bf16* __restrict__ dst, int n) {
    int i = (blockIdx.x * 256 + threadIdx.x) * 8;
    if (i >= n) return;
    floatx4 a = *(const floatx4*)(src + i);
    floatx4 b = *(const floatx4*)(src + i + 4);
    bf16x8 o;
    for (int j = 0; j < 4; ++j) { o[j] = (__bf16)a[j]; o[4 + j] = (__bf16)b[j]; }
    *(bf16x8*)(dst + i) = o;
}

// ---------------- LayerNorm: one wave per row of 1024; fp32 in, bf16 out ------------
__global__ __launch_bounds__(64) void ln_kernel(const float* __restrict__ x,
                                                const float* __restrict__ g,
                                                const float* __restrict__ b,
                                                __bf16* __restrict__ out) {
    int row = blockIdx.x, lane = threadIdx.x, base = lane * 16;
    const float* xr = x + (size_t)row * D_MODEL + base;
    float v[16];
    for (int j = 0; j < 4; ++j) {
        floatx4 a = *(const floatx4*)(xr + 4 * j);
        for (int i = 0; i < 4; ++i) v[4 * j + i] = a[i];
    }
    float s = 0.f, sq = 0.f;
    for (int i = 0; i < 16; ++i) { s += v[i]; sq += v[i] * v[i]; }
    for (int o = 1; o < 64; o <<= 1) { s += __shfl_xor(s, o); sq += __shfl_xor(sq, o); }
    float mu = s * (1.0f / D_MODEL);
    float var = sq * (1.0f / D_MODEL) - mu * mu;
    float rstd = rsqrtf(fmaxf(var, 0.f) + 1e-5f);

    const floatx4* gp = (const floatx4*)(g + base);
    const floatx4* bp = (const floatx4*)(b + base);
    bf16x8 o0, o1;
    for (int j = 0; j < 2; ++j) {
        floatx4 gv0 = gp[2 * j], gv1 = gp[2 * j + 1];
        floatx4 bv0 = bp[2 * j], bv1 = bp[2 * j + 1];
        for (int i = 0; i < 4; ++i) {
            float r0 = (v[8 * j + i] - mu) * rstd * gv0[i] + bv0[i];
            float r1 = (v[8 * j + 4 + i] - mu) * rstd * gv1[i] + bv1[i];
            if (j == 0) { o0[i] = (__bf16)r0; o0[4 + i] = (__bf16)r1; }
            else        { o1[i] = (__bf16)r0; o1[4 + i] = (__bf16)r1; }
        }
    }
    bf16x8* op = (bf16x8*)(out + (size_t)row * D_MODEL + base);
    op[0] = o0; op[1] = o1;
}

// ---------------- GEMM: C = A@W^T + bias (+gelu) (+res) -----------------------------
// 128x128 tile, BK=32, 4 waves. Round-5 sync skeleton (2-buffer, ONE __syncthreads
// per K-step, stage(t+1) issued right after the barrier) -- the hand-rolled
// counted-vmcnt variant regressed (m141 failure mode: source-level waitcnt pinning
// defeats compiler scheduling in a 2-barrier loop), so this keeps compiler-managed
// waits. LDS is FRAGMENT-ORDERED (round-6 layout, kept: bank conflicts 4.2M -> 0):
// 8 blocks of 1024B per matrix-tile, block = one MFMA fragment set, read at
// base+lane*16 (conflict-free, imm offsets). global_load_lds per-lane SOURCE
// provides the permutation:
//   block blk=(grp,i): lane l <- M[row=grp*64+i*16+(l&15)][k0+(l>>4)*8 ..+8)
// T1 XCD-aware block swizzle (bijective; all grids have nwg%8==0): consecutive ids
// share the A-row panel -> same-XCD L2 reuse.
// KSPLIT>1: blockIdx.z takes a K-slice, raw fp32 partial; reduce_k2 finishes.
template <typename OutT, bool GELU, bool TRIBIAS, int KSPLIT>
__global__ __launch_bounds__(256) void gemm_bt(const __bf16* __restrict__ A,
                                               const __bf16* __restrict__ W,
                                               const float* __restrict__ bias0,
                                               const float* __restrict__ bias1,
                                               const float* __restrict__ bias2,
                                               const float* __restrict__ res,
                                               OutT* out, float* part1,
                                               int M, int N, int K) {
    __shared__ __bf16 AsF[2][4096];   // 2 buffers x 8 fragment-blocks x 512 elems
    __shared__ __bf16 WsF[2][4096];

    // XCD swizzle: id -> swz (nwg divisible by 8 for all our grids)
    int nwg = gridDim.x * gridDim.y;
    int id = blockIdx.y * gridDim.x + blockIdx.x;
    int cpx = nwg >> 3;
    int swz = (id & 7) * cpx + (id >> 3);
    int m0 = (swz / gridDim.x) * 128, n0 = (swz % gridDim.x) * 128;

    int t = threadIdx.x;
    int lane = t & 63, wave = t >> 6;
    int wm = (wave >> 1) * 64, wn = (wave & 1) * 64;
    int fr = lane & 15, quad = lane >> 4;
    int scol = quad * 8;              // col within 32-col fragment (staging source)

    int Ks = K / KSPLIT;
    int kbeg = (KSPLIT > 1) ? blockIdx.z * Ks : 0;

    floatx4 acc[4][4] = {};

    const __bf16* Abase = A + kbeg;
    const __bf16* Wbase = W + kbeg;

    // stage tile k0 into buffer buf: 2 passes x (1 A-load + 1 W-load) per wave
    auto stage = [&](int buf, int k0) {
#pragma unroll
        for (int p = 0; p < 2; ++p) {
            int blk = p * 4 + wave;
            int row = (blk >> 2) * 64 + (blk & 3) * 16 + fr;
            __builtin_amdgcn_global_load_lds(
                (gbl_void_t*)(Abase + (size_t)(m0 + row) * K + k0 + scol),
                (lds_void_t*)&AsF[buf][blk * 512], 16, 0, 0);
            __builtin_amdgcn_global_load_lds(
                (gbl_void_t*)(Wbase + (size_t)(n0 + row) * K + k0 + scol),
                (lds_void_t*)&WsF[buf][blk * 512], 16, 0, 0);
        }
    };

    auto compute = [&](int buf) {
        bf16x8 af[4], wf[4];
#pragma unroll
        for (int i = 0; i < 4; ++i)
            af[i] = *(const bf16x8*)&AsF[buf][((wave >> 1) * 4 + i) * 512 + lane * 8];
#pragma unroll
        for (int i = 0; i < 4; ++i)
            wf[i] = *(const bf16x8*)&WsF[buf][((wave & 1) * 4 + i) * 512 + lane * 8];
#pragma unroll
        for (int mi = 0; mi < 4; ++mi)
#pragma unroll
            for (int ni = 0; ni < 4; ++ni)
                acc[mi][ni] = __builtin_amdgcn_mfma_f32_16x16x32_bf16(af[mi], wf[ni], acc[mi][ni], 0, 0, 0);
    };

    int nsteps = Ks / 32;
    stage(0, 0);
    for (int s = 0; s < nsteps; ++s) {
        int cur = s & 1;
        __syncthreads();   // buf[cur] staged (vmcnt drained) + prior reads done
        if (s + 1 < nsteps) stage(cur ^ 1, (s + 1) * 32);
        compute(cur);
    }

    if (KSPLIT > 1) {
        float* pb = (blockIdx.z == 0) ? (float*)out : part1;
#pragma unroll
        for (int ni = 0; ni < 4; ++ni) {
            int col = n0 + wn + ni * 16 + fr;
#pragma unroll
            for (int mi = 0; mi < 4; ++mi)
#pragma unroll
                for (int r = 0; r < 4; ++r) {
                    int row = m0 + wm + mi * 16 + quad * 4 + r;
                    pb[(size_t)row * N + col] = acc[mi][ni][r];
                }
        }
    } else {
#pragma unroll
        for (int ni = 0; ni < 4; ++ni) {
            int col = n0 + wn + ni * 16 + fr;
            const float* bp = bias0;
            int bcol = col;
            if (TRIBIAS) { bp = col < 1024 ? bias0 : (col < 2048 ? bias1 : bias2); bcol = col & 1023; }
            float bv = bp[bcol];
#pragma unroll
            for (int mi = 0; mi < 4; ++mi) {
#pragma unroll
                for (int r = 0; r < 4; ++r) {
                    int row = m0 + wm + mi * 16 + quad * 4 + r;
                    float v = acc[mi][ni][r] + bv;
                    if (GELU) v = gelu_exact(v);
                    if (res) v += res[(size_t)row * N + col];
                    out[(size_t)row * N + col] = (OutT)v;
                }
            }
        }
    }
}

// ---------------- split-K reduce: out = p0 + p1 + res + bias (N=1024 pow2) ----------
__global__ __launch_bounds__(256) void reduce_k2(const float* __restrict__ p0,
                                                 const float* p1,
                                                 const float* __restrict__ res,
                                                 const float* __restrict__ bias,
                                                 float* out) {
    int i = (blockIdx.x * 256 + threadIdx.x) * 4;
    floatx4 a = *(const floatx4*)(p0 + i);
    floatx4 b = *(const floatx4*)(p1 + i);
    floatx4 r = *(const floatx4*)(res + i);
    floatx4 bv = *(const floatx4*)(bias + (i & 1023));
    floatx4 o;
#pragma unroll
    for (int j = 0; j < 4; ++j) o[j] = a[j] + b[j] + r[j] + bv[j];
    *(floatx4*)(out + i) = o;
}

// ---------------- V transpose: qkv v-part [b][s][2048+h*64+d] -> vt[b][h][d][s] -----
__global__ __launch_bounds__(256) void transpose_v(const __bf16* __restrict__ qkv,
                                                   __bf16* __restrict__ vt) {
    __shared__ __bf16 tile[64][72];
    int b = blockIdx.z, h = blockIdx.y, s0 = blockIdx.x * 64;
    int t = threadIdx.x;
    int dl = (t & 7) * 8, sl = t >> 3;
    for (int p = 0; p < 2; ++p) {
        int s = sl + p * 32;
        bf16x8 val = *(const bf16x8*)(qkv + (size_t)(b * SEQ + s0 + s) * QKVS + 2048 + h * DK + dl);
        *(bf16x8*)&tile[s][dl] = val;
    }
    __syncthreads();
    int sl2 = (t & 7) * 8, d = t >> 3;
    for (int p = 0; p < 2; ++p) {
        int dd = d + p * 32;
        bf16x8 val;
        for (int j = 0; j < 8; ++j) val[j] = tile[sl2 + j][dd];
        *(bf16x8*)(vt + ((size_t)(b * NH + h) * DK + dd) * SEQ + s0 + sl2) = val;
    }
}

// ---------------- Flash attention, 32 queries/wave, fragment-ordered LDS K/V --------
// (unchanged from round 5 -- left the top-5)
__global__ __launch_bounds__(256, 2) void attn_kernel(const __bf16* __restrict__ qkv,
                                                      const __bf16* __restrict__ vt,
                                                      __bf16* __restrict__ ctx) {
    __shared__ __bf16 Klds[8192];        // 16 blocks x 1024B, block (f,half)=f*2+half
    __shared__ __bf16 Vlds[8192];        // 16 blocks x 1024B, block (c,ti)=c*4+ti
    __shared__ __bf16 Plds[4][32][136];  // [wave][query 32][128 keys + 8 pad]
    int b = blockIdx.z, h = blockIdx.y;
    int wave = threadIdx.x >> 6, lane = threadIdx.x & 63;
    int q0 = blockIdx.x * 128 + wave * 32;
    int fr = lane & 15, quad = lane >> 4;
    const float sc2 = 0.18033688011112042f;   // (1/sqrt(64)) * log2(e)

    const __bf16* qp0 = qkv + (size_t)(b * SEQ + q0 + fr) * QKVS + h * DK + quad * 8;
    const __bf16* qp1 = qp0 + (size_t)16 * QKVS;
    bf16x8 qA0 = *(const bf16x8*)qp0, qB0 = *(const bf16x8*)(qp0 + 32);
    bf16x8 qA1 = *(const bf16x8*)qp1, qB1 = *(const bf16x8*)(qp1 + 32);

    const __bf16* kg = qkv + (size_t)b * SEQ * QKVS + 1024 + h * DK;  // + key*QKVS + d
    const __bf16* vg = vt + (size_t)(b * NH + h) * DK * SEQ;          // + d*SEQ + key

    floatx4 o[8] = {};   // [hh*4+ti]: row=query hh*16+quad*4+r, col=d ti*16+fr
    float m0q = -1e30f, l0q = 0.f, m1q = -1e30f, l1q = 0.f;

    auto stage_tile = [&](int k0) {
#pragma unroll
        for (int p = 0; p < 4; ++p) {
            int bid = wave * 4 + p;
            int f = bid >> 1, half = bid & 1;
            __builtin_amdgcn_global_load_lds(
                (gbl_void_t*)(kg + (size_t)(k0 + f * 16 + fr) * QKVS + quad * 8 + half * 32),
                (lds_void_t*)&Klds[bid * 512], 16, 0, 0);
            int c = bid >> 2, ti = bid & 3;
            __builtin_amdgcn_global_load_lds(
                (gbl_void_t*)(vg + (size_t)(ti * 16 + fr) * SEQ + k0 + c * 32 + quad * 8),
                (lds_void_t*)&Vlds[bid * 512], 16, 0, 0);
        }
    };

    stage_tile(0);
    __syncthreads();   // drains vmcnt -> tile 0 in LDS

    for (int k0 = 0; k0 < SEQ; k0 += 128) {
        const __bf16* Kb = Klds + lane * 8;
        const __bf16* Vb = Vlds + lane * 8;
        bf16x8 kA[8], kB[8];
#pragma unroll
        for (int f = 0; f < 8; ++f) {
            kA[f] = *(const bf16x8*)(Kb + (f * 2 + 0) * 512);
            kB[f] = *(const bf16x8*)(Kb + (f * 2 + 1) * 512);
        }

        // ---- QK^T half 0 ----
        floatx4 s[8];
#pragma unroll
        for (int f = 0; f < 8; ++f) {
            floatx4 z = {0.f, 0.f, 0.f, 0.f};
            z = __builtin_amdgcn_mfma_f32_16x16x32_bf16(kA[f], qA0, z, 0, 0, 0);
            s[f] = __builtin_amdgcn_mfma_f32_16x16x32_bf16(kB[f], qB0, z, 0, 0, 0);
        }
        // ---- softmax half 0 ----
        {
            float fm[8];
#pragma unroll
            for (int f = 0; f < 8; ++f)
                fm[f] = fmaxf(fmaxf(s[f][0], s[f][1]), fmaxf(s[f][2], s[f][3]));
            float mx = fmaxf(fmaxf(fmaxf(fm[0], fm[1]), fmaxf(fm[2], fm[3])),
                             fmaxf(fmaxf(fm[4], fm[5]), fmaxf(fm[6], fm[7])));
            float mx2 = mx * sc2;
            mx2 = fmaxf(mx2, __shfl_xor(mx2, 16));
            mx2 = fmaxf(mx2, __shfl_xor(mx2, 32));
            float mn = fmaxf(m0q, mx2);
            float alpha = EXP2(m0q - mn);
            m0q = mn;
            float r0 = 0.f, r1 = 0.f, r2 = 0.f, r3 = 0.f;
#pragma unroll
            for (int f = 0; f < 8; ++f) {
                bf16x4 pk;
                float p0 = EXP2(fmaf(s[f][0], sc2, -mn));
                float p1 = EXP2(fmaf(s[f][1], sc2, -mn));
                float p2 = EXP2(fmaf(s[f][2], sc2, -mn));
                float p3 = EXP2(fmaf(s[f][3], sc2, -mn));
                r0 += p0; r1 += p1; r2 += p2; r3 += p3;
                pk[0] = (__bf16)p0; pk[1] = (__bf16)p1; pk[2] = (__bf16)p2; pk[3] = (__bf16)p3;
                *(bf16x4*)&Plds[wave][fr][f * 16 + quad * 4] = pk;
            }
            float rs = (r0 + r1) + (r2 + r3);
            rs += __shfl_xor(rs, 16);
            rs += __shfl_xor(rs, 32);
            l0q = l0q * alpha + rs;
            float aB[4];
#pragma unroll
            for (int r = 0; r < 4; ++r) aB[r] = __shfl(alpha, quad * 4 + r);
#pragma unroll
            for (int ti = 0; ti < 4; ++ti)
#pragma unroll
                for (int r = 0; r < 4; ++r) o[ti][r] *= aB[r];
        }

        // ---- QK^T half 1 ----
        floatx4 s1[8];
#pragma unroll
        for (int f = 0; f < 8; ++f) {
            floatx4 z = {0.f, 0.f, 0.f, 0.f};
            z = __builtin_amdgcn_mfma_f32_16x16x32_bf16(kA[f], qA1, z, 0, 0, 0);
            s1[f] = __builtin_amdgcn_mfma_f32_16x16x32_bf16(kB[f], qB1, z, 0, 0, 0);
        }

        // ---- V fragment reads (K regs free) ----
        bf16x8 vf[4][4];
#pragma unroll
        for (int c = 0; c < 4; ++c)
#pragma unroll
            for (int ti = 0; ti < 4; ++ti)
                vf[c][ti] = *(const bf16x8*)(Vb + (c * 4 + ti) * 512);

        __syncthreads();   // all waves done reading K/V LDS
        if (k0 + 128 < SEQ) stage_tile(k0 + 128);   // loads fly under softmax h1 + PV

        // ---- softmax half 1 ----
        {
            float fm[8];
#pragma unroll
            for (int f = 0; f < 8; ++f)
                fm[f] = fmaxf(fmaxf(s1[f][0], s1[f][1]), fmaxf(s1[f][2], s1[f][3]));
            float mx = fmaxf(fmaxf(fmaxf(fm[0], fm[1]), fmaxf(fm[2], fm[3])),
                             fmaxf(fmaxf(fm[4], fm[5]), fmaxf(fm[6], fm[7])));
            float mx2 = mx * sc2;
            mx2 = fmaxf(mx2, __shfl_xor(mx2, 16));
            mx2 = fmaxf(mx2, __shfl_xor(mx2, 32));
            float mn = fmaxf(m1q, mx2);
            float alpha = EXP2(m1q - mn);
            m1q = mn;
            float r0 = 0.f, r1 = 0.f, r2 = 0.f, r3 = 0.f;
#pragma unroll
            for (int f = 0; f < 8; ++f) {
                bf16x4 pk;
                float p0 = EXP2(fmaf(s1[f][0], sc2, -mn));
                float p1 = EXP2(fmaf(s1[f][1], sc2, -mn));
                float p2 = EXP2(fmaf(s1[f][2], sc2, -mn));
                float p3 = EXP2(fmaf(s1[f][3], sc2, -mn));
                r0 += p0; r1 += p1; r2 += p2; r3 += p3;
                pk[0] = (__bf16)p0; pk[1] = (__bf16)p1; pk[2] = (__bf16)p2; pk[3] = (__bf16)p3;
                *(bf16x4*)&Plds[wave][16 + fr][f * 16 + quad * 4] = pk;
            }
            float rs = (r0 + r1) + (r2 + r3);
            rs += __shfl_xor(rs, 16);
            rs += __shfl_xor(rs, 32);
            l1q = l1q * alpha + rs;
            float aB[4];
#pragma unroll
            for (int r = 0; r < 4; ++r) aB[r] = __shfl(alpha, quad * 4 + r);
#pragma unroll
            for (int ti = 0; ti < 4; ++ti)
#pragma unroll
                for (int r = 0; r < 4; ++r) o[4 + ti][r] *= aB[r];
        }
        __threadfence_block();   // order wave-private Plds writes -> cross-lane reads

        // ---- PV both halves ----
        bf16x8 pa0[4], pa1[4];
#pragma unroll
        for (int c = 0; c < 4; ++c) {
            pa0[c] = *(const bf16x8*)&Plds[wave][fr][c * 32 + quad * 8];
            pa1[c] = *(const bf16x8*)&Plds[wave][16 + fr][c * 32 + quad * 8];
        }
#pragma unroll
        for (int c = 0; c < 4; ++c)
#pragma unroll
            for (int ti = 0; ti < 4; ++ti) {
                o[ti]     = __builtin_amdgcn_mfma_f32_16x16x32_bf16(pa0[c], vf[c][ti], o[ti], 0, 0, 0);
                o[4 + ti] = __builtin_amdgcn_mfma_f32_16x16x32_bf16(pa1[c], vf[c][ti], o[4 + ti], 0, 0, 0);
            }
        __threadfence_block();   // P reads done before next iteration's writes

        __syncthreads();   // drains vmcnt -> staged tile t+1 ready in LDS
    }
    float lB0[4], lB1[4];
#pragma unroll
    for (int r = 0; r < 4; ++r) {
        lB0[r] = __shfl(l0q, quad * 4 + r);
        lB1[r] = __shfl(l1q, quad * 4 + r);
    }
#pragma unroll
    for (int ti = 0; ti < 4; ++ti)
#pragma unroll
        for (int r = 0; r < 4; ++r) {
            ctx[(size_t)(b * SEQ + q0 + quad * 4 + r) * D_MODEL + h * DK + ti * 16 + fr] =
                (__bf16)(o[ti][r] / lB0[r]);
            ctx[(size_t)(b * SEQ + q0 + 16 + quad * 4 + r) * D_MODEL + h * DK + ti * 16 + fr] =
                (__bf16)(o[4 + ti][r] / lB1[r]);
        }
}

// -----------------------------------------------------------------------------------
// Workspace 72 MiB:
//   [0,6M):   wqkvB    [6,8M): woB    [8,16M): w1B    [16,24M): w2B
//   [24,40M): h1 -> x1 fp32 trunk
//   [40,64M): qkv      [64,72M): vt
//   AO split-K partials:  [40,56M) + [56,72M)  (qkv/vt dead after attn)
//   ffh = [40,72M) after AO reduce
//   FF2 split-K partials: [0,16M) (wqkvB/woB/w1B dead) + d_out (h2 dead)
//   d_out:    ctx -> h2 -> FF2 partial1 -> final out
extern "C" void kernel_launch(void* const* d_in, const int* in_sizes, int n_in,
                              void* d_out, int out_size, void* d_ws, size_t ws_size,
                              hipStream_t stream) {
    const float* x   = (const float*)d_in[0];
    const float* wq  = (const float*)d_in[1];
    const float* bq  = (const float*)d_in[2];
    const float* wk  = (const float*)d_in[3];
    const float* bk  = (const float*)d_in[4];
    const float* wv  = (const float*)d_in[5];
    const float* bv  = (const float*)d_in[6];
    const float* wo  = (const float*)d_in[7];
    const float* bo  = (const float*)d_in[8];
    const float* w1  = (const float*)d_in[9];
    const float* b1  = (const float*)d_in[10];
    const float* w2  = (const float*)d_in[11];
    const float* b2  = (const float*)d_in[12];
    const float* g1  = (const float*)d_in[13];
    const float* be1 = (const float*)d_in[14];
    const float* g2  = (const float*)d_in[15];
    const float* be2 = (const float*)d_in[16];
    float* out = (float*)d_out;

    char* ws = (char*)d_ws;
    const size_t MB = 1024 * 1024;
    __bf16* wqkvB = (__bf16*)(ws);                 // [0,6M)
    __bf16* woB   = (__bf16*)(ws + 6 * MB);
    __bf16* w1B   = (__bf16*)(ws + 8 * MB);
    __bf16* w2B   = (__bf16*)(ws + 16 * MB);
    __bf16* h1    = (__bf16*)(ws + 24 * MB);       // dead after qkv-gemm
    float*  x1    = (float*)(ws + 24 * MB);        // fp32 trunk [24,40M)
    __bf16* qkv   = (__bf16*)(ws + 40 * MB);       // [40,64M)
    __bf16* vt    = (__bf16*)(ws + 64 * MB);       // [64,72M)
    __bf16* ffh   = (__bf16*)(ws + 40 * MB);       // [40,72M) after qkv+vt die
    float*  pA0   = (float*)(ws + 40 * MB);        // AO partial z=0
    float*  pA1   = (float*)(ws + 56 * MB);        // AO partial z=1
    float*  pF0   = (float*)(ws);                  // FF2 partial z=0 [0,16M)
    __bf16* ctx   = (__bf16*)d_out;                // d_out scratch [0,8M)
    __bf16* h2    = (__bf16*)d_out;                // d_out scratch (after ctx dies)

    const int NDD = D_MODEL * D_MODEL;   // 1M
    const int NDF = D_MODEL * DFF;       // 4M
    cast_f32_bf16<<<NDD / 2048, 256, 0, stream>>>(wq, wqkvB, NDD);
    cast_f32_bf16<<<NDD / 2048, 256, 0, stream>>>(wk, wqkvB + NDD, NDD);
    cast_f32_bf16<<<NDD / 2048, 256, 0, stream>>>(wv, wqkvB + 2 * NDD, NDD);
    cast_f32_bf16<<<NDD / 2048, 256, 0, stream>>>(wo, woB, NDD);
    cast_f32_bf16<<<NDF / 2048, 256, 0, stream>>>(w1, w1B, NDF);
    cast_f32_bf16<<<NDF / 2048, 256, 0, stream>>>(w2, w2B, NDF);

    dim3 gQKV(QKVS / 128, NTOK / 128);       // (24, 32) = 768 blocks
    dim3 gDz(D_MODEL / 128, NTOK / 128, 2);  // (8, 32, 2) = 512 blocks, split-K=2
    dim3 gF(DFF / 128, NTOK / 128);          // (32, 32) = 1024 blocks
    dim3 gTr(SEQ / 64, NH, BATCH);           // (32, 16, 2) transpose_v
    dim3 gAttn(SEQ / 128, NH, BATCH);        // (16, 16, 2) = 512 blocks, 2/CU
    int gRed = NTOK * D_MODEL / (256 * 4);   // 4096 blocks

    // 1. h1 = LN(x, g1, be1)
    ln_kernel<<<NTOK, 64, 0, stream>>>(x, g1, be1, h1);
    // 2. qkv = h1 @ [wq;wk;wv]^T + [bq;bk;bv]   (fused, N=3072)
    gemm_bt<__bf16, false, true, 1><<<gQKV, 256, 0, stream>>>(h1, wqkvB, bq, bk, bv, nullptr, qkv, nullptr, NTOK, QKVS, D_MODEL);
    // 3. vt = transpose(v) per head
    transpose_v<<<gTr, 256, 0, stream>>>(qkv, vt);
    // 4. ctx = softmax(q k^T / sqrt(dk)) v   (writes d_out)
    attn_kernel<<<gAttn, 256, 0, stream>>>(qkv, vt, ctx);
    // 5. x1 = x + ctx @ wo^T + bo   (split-K=2: partials over dead qkv/vt, then reduce)
    gemm_bt<float, false, false, 2><<<gDz, 256, 0, stream>>>(ctx, woB, nullptr, nullptr, nullptr, nullptr, pA0, pA1, NTOK, D_MODEL, D_MODEL);
    reduce_k2<<<gRed, 256, 0, stream>>>(pA0, pA1, x, bo, x1);
    // 6. h2 = LN(x1, g2, be2)   (d_out scratch)
    ln_kernel<<<NTOK, 64, 0, stream>>>(x1, g2, be2, h2);
    // 7. ffh = gelu(h2 @ w1^T + b1)   (full 32 MiB over qkv+vt)
    gemm_bt<__bf16, true, false, 1><<<gF, 256, 0, stream>>>(h2, w1B, b1, b1, b1, nullptr, ffh, nullptr, NTOK, DFF, D_MODEL);
    // 8. out = x1 + ffh @ w2^T + b2   (split-K=2: p0=[0,16M), p1=d_out, reduce in place)
    gemm_bt<float, false, false, 2><<<gDz, 256, 0, stream>>>(ffh, w2B, nullptr, nullptr, nullptr, nullptr, pF0, (float*)d_out, NTOK, D_MODEL, DFF);
    reduce_k2<<<gRed, 256, 0, stream>>>(pF0, (float*)d_out, x1, b2, out);
}

// Round 9
// 462.180 us; speedup vs baseline: 1.0264x; 1.0208x over previous
//
#include <hip/hip_runtime.h>

typedef __attribute__((ext_vector_type(8))) __bf16 bf16x8;
typedef __attribute__((ext_vector_type(4))) __bf16 bf16x4;
typedef __attribute__((ext_vector_type(4))) float floatx4;
typedef void __attribute__((address_space(3))) lds_void_t;
typedef const void __attribute__((address_space(1))) gbl_void_t;

#define D_MODEL 1024
#define SEQ     2048
#define BATCH   2
#define NH      16
#define DK      64
#define DFF     4096
#define NTOK    (BATCH * SEQ)   // 4096
#define QKVS    3072            // fused qkv row stride

#if __has_builtin(__builtin_amdgcn_exp2f)
#define EXP2(x) __builtin_amdgcn_exp2f(x)
#else
#define EXP2(x) exp2f(x)
#endif

__device__ __forceinline__ float gelu_exact(float x) {
    return 0.5f * x * (1.0f + erff(x * 0.70710678118654752f));
}

// ---------------- fused fp32 -> bf16 weight cast (all 6 weights, one launch) --------
// block ranges (each block casts 2048 elems; NDD8 = 512 blocks per 1M-elem matrix):
//   [0,512) wq | [512,1024) wk | [1024,1536) wv | [1536,2048) wo
//   [2048,4096) w1 (2048 blocks) | [4096,6144) w2 (2048 blocks)
// ROUND-8 BUG FIX: w1 branch condition was 12*NDD8 (=6144) instead of 8*NDD8 (=4096)
// -> OOB reads past w1 (core dump) + w2B never cast. Fixed constants below.
__global__ __launch_bounds__(256) void cast_all(const float* __restrict__ wq,
                                                const float* __restrict__ wk,
                                                const float* __restrict__ wv,
                                                const float* __restrict__ wo,
                                                const float* __restrict__ w1,
                                                const float* __restrict__ w2,
                                                __bf16* __restrict__ wqkvB,
                                                __bf16* __restrict__ woB,
                                                __bf16* __restrict__ w1B,
                                                __bf16* __restrict__ w2B) {
    int blk = blockIdx.x;
    const float* src;
    __bf16* dst;
    int base;
    const int NDD8 = (D_MODEL * D_MODEL) / 2048;   // 512
    if (blk < NDD8)          { src = wq; dst = wqkvB;                     base = blk; }
    else if (blk < 2 * NDD8) { src = wk; dst = wqkvB + D_MODEL * D_MODEL; base = blk - NDD8; }
    else if (blk < 3 * NDD8) { src = wv; dst = wqkvB + 2 * D_MODEL * D_MODEL; base = blk - 2 * NDD8; }
    else if (blk < 4 * NDD8) { src = wo; dst = woB;                       base = blk - 3 * NDD8; }
    else if (blk < 8 * NDD8) { src = w1; dst = w1B;                       base = blk - 4 * NDD8; }
    else                     { src = w2; dst = w2B;                       base = blk - 8 * NDD8; }
    int i = (base * 256 + threadIdx.x) * 8;
    floatx4 a = *(const floatx4*)(src + i);
    floatx4 b = *(const floatx4*)(src + i + 4);
    bf16x8 o;
    for (int j = 0; j < 4; ++j) { o[j] = (__bf16)a[j]; o[4 + j] = (__bf16)b[j]; }
    *(bf16x8*)(dst + i) = o;
}

// ---------------- LayerNorm: one wave per row of 1024; fp32 in, bf16 out ------------
__global__ __launch_bounds__(64) void ln_kernel(const float* __restrict__ x,
                                                const float* __restrict__ g,
                                                const float* __restrict__ b,
                                                __bf16* __restrict__ out) {
    int row = blockIdx.x, lane = threadIdx.x, base = lane * 16;
    const float* xr = x + (size_t)row * D_MODEL + base;
    float v[16];
    for (int j = 0; j < 4; ++j) {
        floatx4 a = *(const floatx4*)(xr + 4 * j);
        for (int i = 0; i < 4; ++i) v[4 * j + i] = a[i];
    }
    float s = 0.f, sq = 0.f;
    for (int i = 0; i < 16; ++i) { s += v[i]; sq += v[i] * v[i]; }
    for (int o = 1; o < 64; o <<= 1) { s += __shfl_xor(s, o); sq += __shfl_xor(sq, o); }
    float mu = s * (1.0f / D_MODEL);
    float var = sq * (1.0f / D_MODEL) - mu * mu;
    float rstd = rsqrtf(fmaxf(var, 0.f) + 1e-5f);

    const floatx4* gp = (const floatx4*)(g + base);
    const floatx4* bp = (const floatx4*)(b + base);
    bf16x8 o0, o1;
    for (int j = 0; j < 2; ++j) {
        floatx4 gv0 = gp[2 * j], gv1 = gp[2 * j + 1];
        floatx4 bv0 = bp[2 * j], bv1 = bp[2 * j + 1];
        for (int i = 0; i < 4; ++i) {
            float r0 = (v[8 * j + i] - mu) * rstd * gv0[i] + bv0[i];
            float r1 = (v[8 * j + 4 + i] - mu) * rstd * gv1[i] + bv1[i];
            if (j == 0) { o0[i] = (__bf16)r0; o0[4 + i] = (__bf16)r1; }
            else        { o1[i] = (__bf16)r0; o1[4 + i] = (__bf16)r1; }
        }
    }
    bf16x8* op = (bf16x8*)(out + (size_t)row * D_MODEL + base);
    op[0] = o0; op[1] = o1;
}

// ---------------- fused split-K reduce + LayerNorm (AO tail) ------------------------
// x1 = p0 + p1 + res + bias;  h2 = LN(x1, g, be).  One wave per row. Saves the
// x1 write->read round trip between reduce_k2 and ln_kernel plus a launch.
__global__ __launch_bounds__(64) void reduce_ln(const float* __restrict__ p0,
                                                const float* __restrict__ p1,
                                                const float* __restrict__ res,
                                                const float* __restrict__ bias,
                                                const float* __restrict__ g,
                                                const float* __restrict__ be,
                                                float* __restrict__ x1,
                                                __bf16* __restrict__ h2) {
    int row = blockIdx.x, lane = threadIdx.x, base = lane * 16;
    size_t off = (size_t)row * D_MODEL + base;
    float v[16];
    for (int j = 0; j < 4; ++j) {
        floatx4 a = *(const floatx4*)(p0 + off + 4 * j);
        floatx4 b = *(const floatx4*)(p1 + off + 4 * j);
        floatx4 r = *(const floatx4*)(res + off + 4 * j);
        floatx4 bv = *(const floatx4*)(bias + base + 4 * j);
        floatx4 o;
        for (int i = 0; i < 4; ++i) { o[i] = a[i] + b[i] + r[i] + bv[i]; v[4 * j + i] = o[i]; }
        *(floatx4*)(x1 + off + 4 * j) = o;
    }
    float s = 0.f, sq = 0.f;
    for (int i = 0; i < 16; ++i) { s += v[i]; sq += v[i] * v[i]; }
    for (int o = 1; o < 64; o <<= 1) { s += __shfl_xor(s, o); sq += __shfl_xor(sq, o); }
    float mu = s * (1.0f / D_MODEL);
    float var = sq * (1.0f / D_MODEL) - mu * mu;
    float rstd = rsqrtf(fmaxf(var, 0.f) + 1e-5f);

    const floatx4* gp = (const floatx4*)(g + base);
    const floatx4* bp = (const floatx4*)(be + base);
    bf16x8 o0, o1;
    for (int j = 0; j < 2; ++j) {
        floatx4 gv0 = gp[2 * j], gv1 = gp[2 * j + 1];
        floatx4 bv0 = bp[2 * j], bv1 = bp[2 * j + 1];
        for (int i = 0; i < 4; ++i) {
            float r0 = (v[8 * j + i] - mu) * rstd * gv0[i] + bv0[i];
            float r1 = (v[8 * j + 4 + i] - mu) * rstd * gv1[i] + bv1[i];
            if (j == 0) { o0[i] = (__bf16)r0; o0[4 + i] = (__bf16)r1; }
            else        { o1[i] = (__bf16)r0; o1[4 + i] = (__bf16)r1; }
        }
    }
    bf16x8* op = (bf16x8*)(h2 + off);
    op[0] = o0; op[1] = o1;
}

// ---------------- GEMM: C = A@W^T + bias (+gelu) (+res) -----------------------------
// 128x128 tile, BK=32, 4 waves. 2-buffer, ONE __syncthreads per K-step, stage(t+1)
// issued right after the barrier (best-measured skeleton; counted-vmcnt variant
// regressed -- m141 failure mode). LDS is FRAGMENT-ORDERED (bank conflicts = 0):
// 8 blocks of 1024B per matrix-tile, block = one MFMA fragment set, read at
// base+lane*16 (conflict-free, imm offsets). global_load_lds per-lane SOURCE
// provides the permutation:
//   block blk=(grp,i): lane l <- M[row=grp*64+i*16+(l&15)][k0+(l>>4)*8 ..+8)
// NO XCD swizzle: operands are L3-resident here; swizzle measured FETCH 41->70MB
// (T1 only pays in the HBM-bound regime, and costs when L3-fit).
// KSPLIT>1: blockIdx.z takes a K-slice, raw fp32 partial; reduce finishes.
template <typename OutT, bool GELU, bool TRIBIAS, int KSPLIT>
__global__ __launch_bounds__(256) void gemm_bt(const __bf16* __restrict__ A,
                                               const __bf16* __restrict__ W,
                                               const float* __restrict__ bias0,
                                               const float* __restrict__ bias1,
                                               const float* __restrict__ bias2,
                                               const float* __restrict__ res,
                                               OutT* out, float* part1,
                                               int M, int N, int K) {
    __shared__ __bf16 AsF[2][4096];   // 2 buffers x 8 fragment-blocks x 512 elems
    __shared__ __bf16 WsF[2][4096];

    int m0 = blockIdx.y * 128, n0 = blockIdx.x * 128;
    int t = threadIdx.x;
    int lane = t & 63, wave = t >> 6;
    int wm = (wave >> 1) * 64, wn = (wave & 1) * 64;
    int fr = lane & 15, quad = lane >> 4;
    int scol = quad * 8;              // col within 32-col fragment (staging source)

    int Ks = K / KSPLIT;
    int kbeg = (KSPLIT > 1) ? blockIdx.z * Ks : 0;

    floatx4 acc[4][4] = {};

    const __bf16* Abase = A + kbeg;
    const __bf16* Wbase = W + kbeg;

    // stage tile k0 into buffer buf: 2 passes x (1 A-load + 1 W-load) per wave
    auto stage = [&](int buf, int k0) {
#pragma unroll
        for (int p = 0; p < 2; ++p) {
            int blk = p * 4 + wave;
            int row = (blk >> 2) * 64 + (blk & 3) * 16 + fr;
            __builtin_amdgcn_global_load_lds(
                (gbl_void_t*)(Abase + (size_t)(m0 + row) * K + k0 + scol),
                (lds_void_t*)&AsF[buf][blk * 512], 16, 0, 0);
            __builtin_amdgcn_global_load_lds(
                (gbl_void_t*)(Wbase + (size_t)(n0 + row) * K + k0 + scol),
                (lds_void_t*)&WsF[buf][blk * 512], 16, 0, 0);
        }
    };

    auto compute = [&](int buf) {
        bf16x8 af[4], wf[4];
#pragma unroll
        for (int i = 0; i < 4; ++i)
            af[i] = *(const bf16x8*)&AsF[buf][((wave >> 1) * 4 + i) * 512 + lane * 8];
#pragma unroll
        for (int i = 0; i < 4; ++i)
            wf[i] = *(const bf16x8*)&WsF[buf][((wave & 1) * 4 + i) * 512 + lane * 8];
#pragma unroll
        for (int mi = 0; mi < 4; ++mi)
#pragma unroll
            for (int ni = 0; ni < 4; ++ni)
                acc[mi][ni] = __builtin_amdgcn_mfma_f32_16x16x32_bf16(af[mi], wf[ni], acc[mi][ni], 0, 0, 0);
    };

    int nsteps = Ks / 32;
    stage(0, 0);
    for (int s = 0; s < nsteps; ++s) {
        int cur = s & 1;
        __syncthreads();   // buf[cur] staged (vmcnt drained) + prior reads done
        if (s + 1 < nsteps) stage(cur ^ 1, (s + 1) * 32);
        compute(cur);
    }

    if (KSPLIT > 1) {
        float* pb = (blockIdx.z == 0) ? (float*)out : part1;
#pragma unroll
        for (int ni = 0; ni < 4; ++ni) {
            int col = n0 + wn + ni * 16 + fr;
#pragma unroll
            for (int mi = 0; mi < 4; ++mi)
#pragma unroll
                for (int r = 0; r < 4; ++r) {
                    int row = m0 + wm + mi * 16 + quad * 4 + r;
                    pb[(size_t)row * N + col] = acc[mi][ni][r];
                }
        }
    } else {
#pragma unroll
        for (int ni = 0; ni < 4; ++ni) {
            int col = n0 + wn + ni * 16 + fr;
            const float* bp = bias0;
            int bcol = col;
            if (TRIBIAS) { bp = col < 1024 ? bias0 : (col < 2048 ? bias1 : bias2); bcol = col & 1023; }
            float bv = bp[bcol];
#pragma unroll
            for (int mi = 0; mi < 4; ++mi) {
#pragma unroll
                for (int r = 0; r < 4; ++r) {
                    int row = m0 + wm + mi * 16 + quad * 4 + r;
                    float v = acc[mi][ni][r] + bv;
                    if (GELU) v = gelu_exact(v);
                    if (res) v += res[(size_t)row * N + col];
                    out[(size_t)row * N + col] = (OutT)v;
                }
            }
        }
    }
}

// ---------------- split-K reduce: out = p0 + p1 + res + bias (N=1024 pow2) ----------
__global__ __launch_bounds__(256) void reduce_k2(const float* __restrict__ p0,
                                                 const float* p1,
                                                 const float* __restrict__ res,
                                                 const float* __restrict__ bias,
                                                 float* out) {
    int i = (blockIdx.x * 256 + threadIdx.x) * 4;
    floatx4 a = *(const floatx4*)(p0 + i);
    floatx4 b = *(const floatx4*)(p1 + i);
    floatx4 r = *(const floatx4*)(res + i);
    floatx4 bv = *(const floatx4*)(bias + (i & 1023));
    floatx4 o;
#pragma unroll
    for (int j = 0; j < 4; ++j) o[j] = a[j] + b[j] + r[j] + bv[j];
    *(floatx4*)(out + i) = o;
}

// ---------------- V transpose: qkv v-part [b][s][2048+h*64+d] -> vt[b][h][d][s] -----
__global__ __launch_bounds__(256) void transpose_v(const __bf16* __restrict__ qkv,
                                                   __bf16* __restrict__ vt) {
    __shared__ __bf16 tile[64][72];
    int b = blockIdx.z, h = blockIdx.y, s0 = blockIdx.x * 64;
    int t = threadIdx.x;
    int dl = (t & 7) * 8, sl = t >> 3;
    for (int p = 0; p < 2; ++p) {
        int s = sl + p * 32;
        bf16x8 val = *(const bf16x8*)(qkv + (size_t)(b * SEQ + s0 + s) * QKVS + 2048 + h * DK + dl);
        *(bf16x8*)&tile[s][dl] = val;
    }
    __syncthreads();
    int sl2 = (t & 7) * 8, d = t >> 3;
    for (int p = 0; p < 2; ++p) {
        int dd = d + p * 32;
        bf16x8 val;
        for (int j = 0; j < 8; ++j) val[j] = tile[sl2 + j][dd];
        *(bf16x8*)(vt + ((size_t)(b * NH + h) * DK + dd) * SEQ + s0 + sl2) = val;
    }
}

// ---------------- Flash attention, 32 queries/wave, fragment-ordered LDS K/V --------
// (unchanged -- not in the top-5)
__global__ __launch_bounds__(256, 2) void attn_kernel(const __bf16* __restrict__ qkv,
                                                      const __bf16* __restrict__ vt,
                                                      __bf16* __restrict__ ctx) {
    __shared__ __bf16 Klds[8192];        // 16 blocks x 1024B, block (f,half)=f*2+half
    __shared__ __bf16 Vlds[8192];        // 16 blocks x 1024B, block (c,ti)=c*4+ti
    __shared__ __bf16 Plds[4][32][136];  // [wave][query 32][128 keys + 8 pad]
    int b = blockIdx.z, h = blockIdx.y;
    int wave = threadIdx.x >> 6, lane = threadIdx.x & 63;
    int q0 = blockIdx.x * 128 + wave * 32;
    int fr = lane & 15, quad = lane >> 4;
    const float sc2 = 0.18033688011112042f;   // (1/sqrt(64)) * log2(e)

    const __bf16* qp0 = qkv + (size_t)(b * SEQ + q0 + fr) * QKVS + h * DK + quad * 8;
    const __bf16* qp1 = qp0 + (size_t)16 * QKVS;
    bf16x8 qA0 = *(const bf16x8*)qp0, qB0 = *(const bf16x8*)(qp0 + 32);
    bf16x8 qA1 = *(const bf16x8*)qp1, qB1 = *(const bf16x8*)(qp1 + 32);

    const __bf16* kg = qkv + (size_t)b * SEQ * QKVS + 1024 + h * DK;  // + key*QKVS + d
    const __bf16* vg = vt + (size_t)(b * NH + h) * DK * SEQ;          // + d*SEQ + key

    floatx4 o[8] = {};   // [hh*4+ti]: row=query hh*16+quad*4+r, col=d ti*16+fr
    float m0q = -1e30f, l0q = 0.f, m1q = -1e30f, l1q = 0.f;

    auto stage_tile = [&](int k0) {
#pragma unroll
        for (int p = 0; p < 4; ++p) {
            int bid = wave * 4 + p;
            int f = bid >> 1, half = bid & 1;
            __builtin_amdgcn_global_load_lds(
                (gbl_void_t*)(kg + (size_t)(k0 + f * 16 + fr) * QKVS + quad * 8 + half * 32),
                (lds_void_t*)&Klds[bid * 512], 16, 0, 0);
            int c = bid >> 2, ti = bid & 3;
            __builtin_amdgcn_global_load_lds(
                (gbl_void_t*)(vg + (size_t)(ti * 16 + fr) * SEQ + k0 + c * 32 + quad * 8),
                (lds_void_t*)&Vlds[bid * 512], 16, 0, 0);
        }
    };

    stage_tile(0);
    __syncthreads();   // drains vmcnt -> tile 0 in LDS

    for (int k0 = 0; k0 < SEQ; k0 += 128) {
        const __bf16* Kb = Klds + lane * 8;
        const __bf16* Vb = Vlds + lane * 8;
        bf16x8 kA[8], kB[8];
#pragma unroll
        for (int f = 0; f < 8; ++f) {
            kA[f] = *(const bf16x8*)(Kb + (f * 2 + 0) * 512);
            kB[f] = *(const bf16x8*)(Kb + (f * 2 + 1) * 512);
        }

        // ---- QK^T half 0 ----
        floatx4 s[8];
#pragma unroll
        for (int f = 0; f < 8; ++f) {
            floatx4 z = {0.f, 0.f, 0.f, 0.f};
            z = __builtin_amdgcn_mfma_f32_16x16x32_bf16(kA[f], qA0, z, 0, 0, 0);
            s[f] = __builtin_amdgcn_mfma_f32_16x16x32_bf16(kB[f], qB0, z, 0, 0, 0);
        }
        // ---- softmax half 0 ----
        {
            float fm[8];
#pragma unroll
            for (int f = 0; f < 8; ++f)
                fm[f] = fmaxf(fmaxf(s[f][0], s[f][1]), fmaxf(s[f][2], s[f][3]));
            float mx = fmaxf(fmaxf(fmaxf(fm[0], fm[1]), fmaxf(fm[2], fm[3])),
                             fmaxf(fmaxf(fm[4], fm[5]), fmaxf(fm[6], fm[7])));
            float mx2 = mx * sc2;
            mx2 = fmaxf(mx2, __shfl_xor(mx2, 16));
            mx2 = fmaxf(mx2, __shfl_xor(mx2, 32));
            float mn = fmaxf(m0q, mx2);
            float alpha = EXP2(m0q - mn);
            m0q = mn;
            float r0 = 0.f, r1 = 0.f, r2 = 0.f, r3 = 0.f;
#pragma unroll
            for (int f = 0; f < 8; ++f) {
                bf16x4 pk;
                float p0 = EXP2(fmaf(s[f][0], sc2, -mn));
                float p1 = EXP2(fmaf(s[f][1], sc2, -mn));
                float p2 = EXP2(fmaf(s[f][2], sc2, -mn));
                float p3 = EXP2(fmaf(s[f][3], sc2, -mn));
                r0 += p0; r1 += p1; r2 += p2; r3 += p3;
                pk[0] = (__bf16)p0; pk[1] = (__bf16)p1; pk[2] = (__bf16)p2; pk[3] = (__bf16)p3;
                *(bf16x4*)&Plds[wave][fr][f * 16 + quad * 4] = pk;
            }
            float rs = (r0 + r1) + (r2 + r3);
            rs += __shfl_xor(rs, 16);
            rs += __shfl_xor(rs, 32);
            l0q = l0q * alpha + rs;
            float aB[4];
#pragma unroll
            for (int r = 0; r < 4; ++r) aB[r] = __shfl(alpha, quad * 4 + r);
#pragma unroll
            for (int ti = 0; ti < 4; ++ti)
#pragma unroll
                for (int r = 0; r < 4; ++r) o[ti][r] *= aB[r];
        }

        // ---- QK^T half 1 ----
        floatx4 s1[8];
#pragma unroll
        for (int f = 0; f < 8; ++f) {
            floatx4 z = {0.f, 0.f, 0.f, 0.f};
            z = __builtin_amdgcn_mfma_f32_16x16x32_bf16(kA[f], qA1, z, 0, 0, 0);
            s1[f] = __builtin_amdgcn_mfma_f32_16x16x32_bf16(kB[f], qB1, z, 0, 0, 0);
        }

        // ---- V fragment reads (K regs free) ----
        bf16x8 vf[4][4];
#pragma unroll
        for (int c = 0; c < 4; ++c)
#pragma unroll
            for (int ti = 0; ti < 4; ++ti)
                vf[c][ti] = *(const bf16x8*)(Vb + (c * 4 + ti) * 512);

        __syncthreads();   // all waves done reading K/V LDS
        if (k0 + 128 < SEQ) stage_tile(k0 + 128);   // loads fly under softmax h1 + PV

        // ---- softmax half 1 ----
        {
            float fm[8];
#pragma unroll
            for (int f = 0; f < 8; ++f)
                fm[f] = fmaxf(fmaxf(s1[f][0], s1[f][1]), fmaxf(s1[f][2], s1[f][3]));
            float mx = fmaxf(fmaxf(fmaxf(fm[0], fm[1]), fmaxf(fm[2], fm[3])),
                             fmaxf(fmaxf(fm[4], fm[5]), fmaxf(fm[6], fm[7])));
            float mx2 = mx * sc2;
            mx2 = fmaxf(mx2, __shfl_xor(mx2, 16));
            mx2 = fmaxf(mx2, __shfl_xor(mx2, 32));
            float mn = fmaxf(m1q, mx2);
            float alpha = EXP2(m1q - mn);
            m1q = mn;
            float r0 = 0.f, r1 = 0.f, r2 = 0.f, r3 = 0.f;
#pragma unroll
            for (int f = 0; f < 8; ++f) {
                bf16x4 pk;
                float p0 = EXP2(fmaf(s1[f][0], sc2, -mn));
                float p1 = EXP2(fmaf(s1[f][1], sc2, -mn));
                float p2 = EXP2(fmaf(s1[f][2], sc2, -mn));
                float p3 = EXP2(fmaf(s1[f][3], sc2, -mn));
                r0 += p0; r1 += p1; r2 += p2; r3 += p3;
                pk[0] = (__bf16)p0; pk[1] = (__bf16)p1; pk[2] = (__bf16)p2; pk[3] = (__bf16)p3;
                *(bf16x4*)&Plds[wave][16 + fr][f * 16 + quad * 4] = pk;
            }
            float rs = (r0 + r1) + (r2 + r3);
            rs += __shfl_xor(rs, 16);
            rs += __shfl_xor(rs, 32);
            l1q = l1q * alpha + rs;
            float aB[4];
#pragma unroll
            for (int r = 0; r < 4; ++r) aB[r] = __shfl(alpha, quad * 4 + r);
#pragma unroll
            for (int ti = 0; ti < 4; ++ti)
#pragma unroll
                for (int r = 0; r < 4; ++r) o[4 + ti][r] *= aB[r];
        }
        __threadfence_block();   // order wave-private Plds writes -> cross-lane reads

        // ---- PV both halves ----
        bf16x8 pa0[4], pa1[4];
#pragma unroll
        for (int c = 0; c < 4; ++c) {
            pa0[c] = *(const bf16x8*)&Plds[wave][fr][c * 32 + quad * 8];
            pa1[c] = *(const bf16x8*)&Plds[wave][16 + fr][c * 32 + quad * 8];
        }
#pragma unroll
        for (int c = 0; c < 4; ++c)
#pragma unroll
            for (int ti = 0; ti < 4; ++ti) {
                o[ti]     = __builtin_amdgcn_mfma_f32_16x16x32_bf16(pa0[c], vf[c][ti], o[ti], 0, 0, 0);
                o[4 + ti] = __builtin_amdgcn_mfma_f32_16x16x32_bf16(pa1[c], vf[c][ti], o[4 + ti], 0, 0, 0);
            }
        __threadfence_block();   // P reads done before next iteration's writes

        __syncthreads();   // drains vmcnt -> staged tile t+1 ready in LDS
    }
    float lB0[4], lB1[4];
#pragma unroll
    for (int r = 0; r < 4; ++r) {
        lB0[r] = __shfl(l0q, quad * 4 + r);
        lB1[r] = __shfl(l1q, quad * 4 + r);
    }
#pragma unroll
    for (int ti = 0; ti < 4; ++ti)
#pragma unroll
        for (int r = 0; r < 4; ++r) {
            ctx[(size_t)(b * SEQ + q0 + quad * 4 + r) * D_MODEL + h * DK + ti * 16 + fr] =
                (__bf16)(o[ti][r] / lB0[r]);
            ctx[(size_t)(b * SEQ + q0 + 16 + quad * 4 + r) * D_MODEL + h * DK + ti * 16 + fr] =
                (__bf16)(o[4 + ti][r] / lB1[r]);
        }
}

// -----------------------------------------------------------------------------------
// Workspace 72 MiB:
//   [0,6M):   wqkvB    [6,8M): woB    [8,16M): w1B    [16,24M): w2B
//   [24,40M): h1 -> x1 fp32 trunk
//   [40,64M): qkv      [64,72M): vt
//   AO split-K partials:  [40,56M) + [56,72M)  (qkv/vt dead after attn)
//   ffh = [40,72M) after AO reduce_ln
//   FF2 split-K partials: [0,16M) (wqkvB/woB/w1B dead) + d_out (h2 dead)
//   d_out:    ctx -> h2 -> FF2 partial1 -> final out
extern "C" void kernel_launch(void* const* d_in, const int* in_sizes, int n_in,
                              void* d_out, int out_size, void* d_ws, size_t ws_size,
                              hipStream_t stream) {
    const float* x   = (const float*)d_in[0];
    const float* wq  = (const float*)d_in[1];
    const float* bq  = (const float*)d_in[2];
    const float* wk  = (const float*)d_in[3];
    const float* bk  = (const float*)d_in[4];
    const float* wv  = (const float*)d_in[5];
    const float* bv  = (const float*)d_in[6];
    const float* wo  = (const float*)d_in[7];
    const float* bo  = (const float*)d_in[8];
    const float* w1  = (const float*)d_in[9];
    const float* b1  = (const float*)d_in[10];
    const float* w2  = (const float*)d_in[11];
    const float* b2  = (const float*)d_in[12];
    const float* g1  = (const float*)d_in[13];
    const float* be1 = (const float*)d_in[14];
    const float* g2  = (const float*)d_in[15];
    const float* be2 = (const float*)d_in[16];
    float* out = (float*)d_out;

    char* ws = (char*)d_ws;
    const size_t MB = 1024 * 1024;
    __bf16* wqkvB = (__bf16*)(ws);                 // [0,6M)
    __bf16* woB   = (__bf16*)(ws + 6 * MB);
    __bf16* w1B   = (__bf16*)(ws + 8 * MB);
    __bf16* w2B   = (__bf16*)(ws + 16 * MB);
    __bf16* h1    = (__bf16*)(ws + 24 * MB);       // dead after qkv-gemm
    float*  x1    = (float*)(ws + 24 * MB);        // fp32 trunk [24,40M)
    __bf16* qkv   = (__bf16*)(ws + 40 * MB);       // [40,64M)
    __bf16* vt    = (__bf16*)(ws + 64 * MB);       // [64,72M)
    __bf16* ffh   = (__bf16*)(ws + 40 * MB);       // [40,72M) after qkv+vt die
    float*  pA0   = (float*)(ws + 40 * MB);        // AO partial z=0
    float*  pA1   = (float*)(ws + 56 * MB);        // AO partial z=1
    float*  pF0   = (float*)(ws);                  // FF2 partial z=0 [0,16M)
    __bf16* ctx   = (__bf16*)d_out;                // d_out scratch [0,8M)
    __bf16* h2    = (__bf16*)d_out;                // d_out scratch (after ctx dies)

    dim3 gQKV(QKVS / 128, NTOK / 128);       // (24, 32) = 768 blocks
    dim3 gDz(D_MODEL / 128, NTOK / 128, 2);  // (8, 32, 2) = 512 blocks, split-K=2
    dim3 gF(DFF / 128, NTOK / 128);          // (32, 32) = 1024 blocks
    dim3 gTr(SEQ / 64, NH, BATCH);           // (32, 16, 2) transpose_v
    dim3 gAttn(SEQ / 128, NH, BATCH);        // (16, 16, 2) = 512 blocks, 2/CU
    int gRed = NTOK * D_MODEL / (256 * 4);   // 4096 blocks

    // 0. all weight casts in one launch (6144 blocks)
    cast_all<<<6144, 256, 0, stream>>>(wq, wk, wv, wo, w1, w2, wqkvB, woB, w1B, w2B);
    // 1. h1 = LN(x, g1, be1)
    ln_kernel<<<NTOK, 64, 0, stream>>>(x, g1, be1, h1);
    // 2. qkv = h1 @ [wq;wk;wv]^T + [bq;bk;bv]   (fused, N=3072)
    gemm_bt<__bf16, false, true, 1><<<gQKV, 256, 0, stream>>>(h1, wqkvB, bq, bk, bv, nullptr, qkv, nullptr, NTOK, QKVS, D_MODEL);
    // 3. vt = transpose(v) per head
    transpose_v<<<gTr, 256, 0, stream>>>(qkv, vt);
    // 4. ctx = softmax(q k^T / sqrt(dk)) v   (writes d_out)
    attn_kernel<<<gAttn, 256, 0, stream>>>(qkv, vt, ctx);
    // 5. AO split-K=2: partials over dead qkv/vt
    gemm_bt<float, false, false, 2><<<gDz, 256, 0, stream>>>(ctx, woB, nullptr, nullptr, nullptr, nullptr, pA0, pA1, NTOK, D_MODEL, D_MODEL);
    // 6. x1 = pA0+pA1+x+bo;  h2 = LN(x1, g2, be2)   (fused reduce+LN; h2 overwrites ctx)
    reduce_ln<<<NTOK, 64, 0, stream>>>(pA0, pA1, x, bo, g2, be2, x1, h2);
    // 7. ffh = gelu(h2 @ w1^T + b1)   (full 32 MiB over qkv+vt)
    gemm_bt<__bf16, true, false, 1><<<gF, 256, 0, stream>>>(h2, w1B, b1, b1, b1, nullptr, ffh, nullptr, NTOK, DFF, D_MODEL);
    // 8. out = x1 + ffh @ w2^T + b2   (split-K=2: p0=[0,16M), p1=d_out, reduce in place)
    gemm_bt<float, false, false, 2><<<gDz, 256, 0, stream>>>(ffh, w2B, nullptr, nullptr, nullptr, nullptr, pF0, (float*)d_out, NTOK, D_MODEL, DFF);
    reduce_k2<<<gRed, 256, 0, stream>>>(pF0, (float*)d_out, x1, b2, out);
}

// Round 10
// 428.981 us; speedup vs baseline: 1.1058x; 1.0774x over previous
//
#include <hip/hip_runtime.h>

typedef __attribute__((ext_vector_type(8))) __bf16 bf16x8;
typedef __attribute__((ext_vector_type(4))) __bf16 bf16x4;
typedef __attribute__((ext_vector_type(4))) float floatx4;
typedef void __attribute__((address_space(3))) lds_void_t;
typedef const void __attribute__((address_space(1))) gbl_void_t;

#define D_MODEL 1024
#define SEQ     2048
#define BATCH   2
#define NH      16
#define DK      64
#define DFF     4096
#define NTOK    (BATCH * SEQ)   // 4096
#define QKVS    3072            // fused qkv row stride

#if __has_builtin(__builtin_amdgcn_exp2f)
#define EXP2(x) __builtin_amdgcn_exp2f(x)
#else
#define EXP2(x) exp2f(x)
#endif

__device__ __forceinline__ float gelu_exact(float x) {
    return 0.5f * x * (1.0f + erff(x * 0.70710678118654752f));
}

// ---------------- fused fp32 -> bf16 weight cast (all 6 weights, one launch) --------
__global__ __launch_bounds__(256) void cast_all(const float* __restrict__ wq,
                                                const float* __restrict__ wk,
                                                const float* __restrict__ wv,
                                                const float* __restrict__ wo,
                                                const float* __restrict__ w1,
                                                const float* __restrict__ w2,
                                                __bf16* __restrict__ wqkvB,
                                                __bf16* __restrict__ woB,
                                                __bf16* __restrict__ w1B,
                                                __bf16* __restrict__ w2B) {
    int blk = blockIdx.x;
    const float* src;
    __bf16* dst;
    int base;
    const int NDD8 = (D_MODEL * D_MODEL) / 2048;   // 512
    if (blk < NDD8)          { src = wq; dst = wqkvB;                     base = blk; }
    else if (blk < 2 * NDD8) { src = wk; dst = wqkvB + D_MODEL * D_MODEL; base = blk - NDD8; }
    else if (blk < 3 * NDD8) { src = wv; dst = wqkvB + 2 * D_MODEL * D_MODEL; base = blk - 2 * NDD8; }
    else if (blk < 4 * NDD8) { src = wo; dst = woB;                       base = blk - 3 * NDD8; }
    else if (blk < 8 * NDD8) { src = w1; dst = w1B;                       base = blk - 4 * NDD8; }
    else                     { src = w2; dst = w2B;                       base = blk - 8 * NDD8; }
    int i = (base * 256 + threadIdx.x) * 8;
    floatx4 a = *(const floatx4*)(src + i);
    floatx4 b = *(const floatx4*)(src + i + 4);
    bf16x8 o;
    for (int j = 0; j < 4; ++j) { o[j] = (__bf16)a[j]; o[4 + j] = (__bf16)b[j]; }
    *(bf16x8*)(dst + i) = o;
}

// ---------------- LayerNorm: one wave per row of 1024; fp32 in, bf16 out ------------
__global__ __launch_bounds__(64) void ln_kernel(const float* __restrict__ x,
                                                const float* __restrict__ g,
                                                const float* __restrict__ b,
                                                __bf16* __restrict__ out) {
    int row = blockIdx.x, lane = threadIdx.x, base = lane * 16;
    const float* xr = x + (size_t)row * D_MODEL + base;
    float v[16];
    for (int j = 0; j < 4; ++j) {
        floatx4 a = *(const floatx4*)(xr + 4 * j);
        for (int i = 0; i < 4; ++i) v[4 * j + i] = a[i];
    }
    float s = 0.f, sq = 0.f;
    for (int i = 0; i < 16; ++i) { s += v[i]; sq += v[i] * v[i]; }
    for (int o = 1; o < 64; o <<= 1) { s += __shfl_xor(s, o); sq += __shfl_xor(sq, o); }
    float mu = s * (1.0f / D_MODEL);
    float var = sq * (1.0f / D_MODEL) - mu * mu;
    float rstd = rsqrtf(fmaxf(var, 0.f) + 1e-5f);

    const floatx4* gp = (const floatx4*)(g + base);
    const floatx4* bp = (const floatx4*)(b + base);
    bf16x8 o0, o1;
    for (int j = 0; j < 2; ++j) {
        floatx4 gv0 = gp[2 * j], gv1 = gp[2 * j + 1];
        floatx4 bv0 = bp[2 * j], bv1 = bp[2 * j + 1];
        for (int i = 0; i < 4; ++i) {
            float r0 = (v[8 * j + i] - mu) * rstd * gv0[i] + bv0[i];
            float r1 = (v[8 * j + 4 + i] - mu) * rstd * gv1[i] + bv1[i];
            if (j == 0) { o0[i] = (__bf16)r0; o0[4 + i] = (__bf16)r1; }
            else        { o1[i] = (__bf16)r0; o1[4 + i] = (__bf16)r1; }
        }
    }
    bf16x8* op = (bf16x8*)(out + (size_t)row * D_MODEL + base);
    op[0] = o0; op[1] = o1;
}

// ---------------- fused split-K reduce + LayerNorm (AO tail) ------------------------
__global__ __launch_bounds__(64) void reduce_ln(const float* __restrict__ p0,
                                                const float* __restrict__ p1,
                                                const float* __restrict__ res,
                                                const float* __restrict__ bias,
                                                const float* __restrict__ g,
                                                const float* __restrict__ be,
                                                float* __restrict__ x1,
                                                __bf16* __restrict__ h2) {
    int row = blockIdx.x, lane = threadIdx.x, base = lane * 16;
    size_t off = (size_t)row * D_MODEL + base;
    float v[16];
    for (int j = 0; j < 4; ++j) {
        floatx4 a = *(const floatx4*)(p0 + off + 4 * j);
        floatx4 b = *(const floatx4*)(p1 + off + 4 * j);
        floatx4 r = *(const floatx4*)(res + off + 4 * j);
        floatx4 bv = *(const floatx4*)(bias + base + 4 * j);
        floatx4 o;
        for (int i = 0; i < 4; ++i) { o[i] = a[i] + b[i] + r[i] + bv[i]; v[4 * j + i] = o[i]; }
        *(floatx4*)(x1 + off + 4 * j) = o;
    }
    float s = 0.f, sq = 0.f;
    for (int i = 0; i < 16; ++i) { s += v[i]; sq += v[i] * v[i]; }
    for (int o = 1; o < 64; o <<= 1) { s += __shfl_xor(s, o); sq += __shfl_xor(sq, o); }
    float mu = s * (1.0f / D_MODEL);
    float var = sq * (1.0f / D_MODEL) - mu * mu;
    float rstd = rsqrtf(fmaxf(var, 0.f) + 1e-5f);

    const floatx4* gp = (const floatx4*)(g + base);
    const floatx4* bp = (const floatx4*)(be + base);
    bf16x8 o0, o1;
    for (int j = 0; j < 2; ++j) {
        floatx4 gv0 = gp[2 * j], gv1 = gp[2 * j + 1];
        floatx4 bv0 = bp[2 * j], bv1 = bp[2 * j + 1];
        for (int i = 0; i < 4; ++i) {
            float r0 = (v[8 * j + i] - mu) * rstd * gv0[i] + bv0[i];
            float r1 = (v[8 * j + 4 + i] - mu) * rstd * gv1[i] + bv1[i];
            if (j == 0) { o0[i] = (__bf16)r0; o0[4 + i] = (__bf16)r1; }
            else        { o1[i] = (__bf16)r0; o1[4 + i] = (__bf16)r1; }
        }
    }
    bf16x8* op = (bf16x8*)(h2 + off);
    op[0] = o0; op[1] = o1;
}

// ---------------- GEMM 128x128 (split-K capable) ------------------------------------
// 2-buffer, ONE __syncthreads per K-step, stage(t+1) after the barrier. LDS
// fragment-ordered (conflicts 0). Used for AO and FF2 (N=1024 -> grid needs split-K).
template <typename OutT, bool GELU, bool TRIBIAS, int KSPLIT>
__global__ __launch_bounds__(256) void gemm_bt(const __bf16* __restrict__ A,
                                               const __bf16* __restrict__ W,
                                               const float* __restrict__ bias0,
                                               const float* __restrict__ bias1,
                                               const float* __restrict__ bias2,
                                               const float* __restrict__ res,
                                               OutT* out, float* part1,
                                               int M, int N, int K) {
    __shared__ __bf16 AsF[2][4096];   // 8 fragment-blocks x 512 elems
    __shared__ __bf16 WsF[2][4096];

    int m0 = blockIdx.y * 128, n0 = blockIdx.x * 128;
    int t = threadIdx.x;
    int lane = t & 63, wave = t >> 6;
    int wm = (wave >> 1) * 64, wn = (wave & 1) * 64;
    int fr = lane & 15, quad = lane >> 4;
    int scol = quad * 8;

    int Ks = K / KSPLIT;
    int kbeg = (KSPLIT > 1) ? blockIdx.z * Ks : 0;

    floatx4 acc[4][4] = {};

    const __bf16* Abase = A + kbeg;
    const __bf16* Wbase = W + kbeg;

    auto stage = [&](int buf, int k0) {
#pragma unroll
        for (int p = 0; p < 2; ++p) {
            int blk = p * 4 + wave;
            int row = (blk >> 2) * 64 + (blk & 3) * 16 + fr;
            __builtin_amdgcn_global_load_lds(
                (gbl_void_t*)(Abase + (size_t)(m0 + row) * K + k0 + scol),
                (lds_void_t*)&AsF[buf][blk * 512], 16, 0, 0);
            __builtin_amdgcn_global_load_lds(
                (gbl_void_t*)(Wbase + (size_t)(n0 + row) * K + k0 + scol),
                (lds_void_t*)&WsF[buf][blk * 512], 16, 0, 0);
        }
    };

    auto compute = [&](int buf) {
        bf16x8 af[4], wf[4];
#pragma unroll
        for (int i = 0; i < 4; ++i)
            af[i] = *(const bf16x8*)&AsF[buf][((wave >> 1) * 4 + i) * 512 + lane * 8];
#pragma unroll
        for (int i = 0; i < 4; ++i)
            wf[i] = *(const bf16x8*)&WsF[buf][((wave & 1) * 4 + i) * 512 + lane * 8];
#pragma unroll
        for (int mi = 0; mi < 4; ++mi)
#pragma unroll
            for (int ni = 0; ni < 4; ++ni)
                acc[mi][ni] = __builtin_amdgcn_mfma_f32_16x16x32_bf16(af[mi], wf[ni], acc[mi][ni], 0, 0, 0);
    };

    int nsteps = Ks / 32;
    stage(0, 0);
    for (int s = 0; s < nsteps; ++s) {
        int cur = s & 1;
        __syncthreads();
        if (s + 1 < nsteps) stage(cur ^ 1, (s + 1) * 32);
        compute(cur);
    }

    if (KSPLIT > 1) {
        float* pb = (blockIdx.z == 0) ? (float*)out : part1;
#pragma unroll
        for (int ni = 0; ni < 4; ++ni) {
            int col = n0 + wn + ni * 16 + fr;
#pragma unroll
            for (int mi = 0; mi < 4; ++mi)
#pragma unroll
                for (int r = 0; r < 4; ++r) {
                    int row = m0 + wm + mi * 16 + quad * 4 + r;
                    pb[(size_t)row * N + col] = acc[mi][ni][r];
                }
        }
    } else {
#pragma unroll
        for (int ni = 0; ni < 4; ++ni) {
            int col = n0 + wn + ni * 16 + fr;
            const float* bp = bias0;
            int bcol = col;
            if (TRIBIAS) { bp = col < 1024 ? bias0 : (col < 2048 ? bias1 : bias2); bcol = col & 1023; }
            float bv = bp[bcol];
#pragma unroll
            for (int mi = 0; mi < 4; ++mi) {
#pragma unroll
                for (int r = 0; r < 4; ++r) {
                    int row = m0 + wm + mi * 16 + quad * 4 + r;
                    float v = acc[mi][ni][r] + bv;
                    if (GELU) v = gelu_exact(v);
                    if (res) v += res[(size_t)row * N + col];
                    out[(size_t)row * N + col] = (OutT)v;
                }
            }
        }
    }
}

// ---------------- GEMM 256x128 tile, 512 threads / 8 waves --------------------------
// Same 1-barrier 2-buffer skeleton and fragment-ordered LDS, but 2x the MFMA work
// per K-step (516 cyc/CU) against 1.5x the staged bytes -- the prefetch window now
// exceeds L2 latency so staging hides under compute without asm scheduling.
// Fragment blocks: A = 16 blocks (row = blk*16+(l&15)), W = 8 blocks. Each of the
// 8 waves stages 3 blocks. Wave (wave>>1, wave&1) owns the 64x64 output sub-tile
// at (wm = (wave>>1)*64, wn = (wave&1)*64). LDS 48KB (2 buf x 24KB) -> 3 blocks/CU.
template <typename OutT, bool GELU, bool TRIBIAS>
__global__ __launch_bounds__(512) void gemm256(const __bf16* __restrict__ A,
                                               const __bf16* __restrict__ W,
                                               const float* __restrict__ bias0,
                                               const float* __restrict__ bias1,
                                               const float* __restrict__ bias2,
                                               OutT* out,
                                               int M, int N, int K) {
    __shared__ __bf16 AsF[2][8192];   // 16 fragment-blocks x 512 elems
    __shared__ __bf16 WsF[2][4096];   // 8 fragment-blocks x 512 elems

    int m0 = blockIdx.y * 256, n0 = blockIdx.x * 128;
    int t = threadIdx.x;
    int lane = t & 63, wave = t >> 6;          // 8 waves
    int wm = (wave >> 1) * 64, wn = (wave & 1) * 64;
    int fr = lane & 15, quad = lane >> 4;
    int scol = quad * 8;

    floatx4 acc[4][4] = {};

    auto stage = [&](int buf, int k0) {
#pragma unroll
        for (int p = 0; p < 3; ++p) {
            int blk = wave * 3 + p;            // 0..23
            if (blk < 16) {                     // A blocks (wave-uniform branch)
                int row = blk * 16 + fr;
                __builtin_amdgcn_global_load_lds(
                    (gbl_void_t*)(A + (size_t)(m0 + row) * K + k0 + scol),
                    (lds_void_t*)&AsF[buf][blk * 512], 16, 0, 0);
            } else {                            // W blocks
                int row = (blk - 16) * 16 + fr;
                __builtin_amdgcn_global_load_lds(
                    (gbl_void_t*)(W + (size_t)(n0 + row) * K + k0 + scol),
                    (lds_void_t*)&WsF[buf][(blk - 16) * 512], 16, 0, 0);
            }
        }
    };

    auto compute = [&](int buf) {
        bf16x8 af[4], wf[4];
#pragma unroll
        for (int i = 0; i < 4; ++i)
            af[i] = *(const bf16x8*)&AsF[buf][((wave >> 1) * 4 + i) * 512 + lane * 8];
#pragma unroll
        for (int i = 0; i < 4; ++i)
            wf[i] = *(const bf16x8*)&WsF[buf][((wave & 1) * 4 + i) * 512 + lane * 8];
#pragma unroll
        for (int mi = 0; mi < 4; ++mi)
#pragma unroll
            for (int ni = 0; ni < 4; ++ni)
                acc[mi][ni] = __builtin_amdgcn_mfma_f32_16x16x32_bf16(af[mi], wf[ni], acc[mi][ni], 0, 0, 0);
    };

    int nsteps = K / 32;
    stage(0, 0);
    for (int s = 0; s < nsteps; ++s) {
        int cur = s & 1;
        __syncthreads();
        if (s + 1 < nsteps) stage(cur ^ 1, (s + 1) * 32);
        compute(cur);
    }

#pragma unroll
    for (int ni = 0; ni < 4; ++ni) {
        int col = n0 + wn + ni * 16 + fr;
        const float* bp = bias0;
        int bcol = col;
        if (TRIBIAS) { bp = col < 1024 ? bias0 : (col < 2048 ? bias1 : bias2); bcol = col & 1023; }
        float bv = bp[bcol];
#pragma unroll
        for (int mi = 0; mi < 4; ++mi) {
#pragma unroll
            for (int r = 0; r < 4; ++r) {
                int row = m0 + wm + mi * 16 + quad * 4 + r;
                float v = acc[mi][ni][r] + bv;
                if (GELU) v = gelu_exact(v);
                out[(size_t)row * N + col] = (OutT)v;
            }
        }
    }
}

// ---------------- split-K reduce: out = p0 + p1 + res + bias (N=1024 pow2) ----------
__global__ __launch_bounds__(256) void reduce_k2(const float* __restrict__ p0,
                                                 const float* p1,
                                                 const float* __restrict__ res,
                                                 const float* __restrict__ bias,
                                                 float* out) {
    int i = (blockIdx.x * 256 + threadIdx.x) * 4;
    floatx4 a = *(const floatx4*)(p0 + i);
    floatx4 b = *(const floatx4*)(p1 + i);
    floatx4 r = *(const floatx4*)(res + i);
    floatx4 bv = *(const floatx4*)(bias + (i & 1023));
    floatx4 o;
#pragma unroll
    for (int j = 0; j < 4; ++j) o[j] = a[j] + b[j] + r[j] + bv[j];
    *(floatx4*)(out + i) = o;
}

// ---------------- V transpose: qkv v-part [b][s][2048+h*64+d] -> vt[b][h][d][s] -----
__global__ __launch_bounds__(256) void transpose_v(const __bf16* __restrict__ qkv,
                                                   __bf16* __restrict__ vt) {
    __shared__ __bf16 tile[64][72];
    int b = blockIdx.z, h = blockIdx.y, s0 = blockIdx.x * 64;
    int t = threadIdx.x;
    int dl = (t & 7) * 8, sl = t >> 3;
    for (int p = 0; p < 2; ++p) {
        int s = sl + p * 32;
        bf16x8 val = *(const bf16x8*)(qkv + (size_t)(b * SEQ + s0 + s) * QKVS + 2048 + h * DK + dl);
        *(bf16x8*)&tile[s][dl] = val;
    }
    __syncthreads();
    int sl2 = (t & 7) * 8, d = t >> 3;
    for (int p = 0; p < 2; ++p) {
        int dd = d + p * 32;
        bf16x8 val;
        for (int j = 0; j < 8; ++j) val[j] = tile[sl2 + j][dd];
        *(bf16x8*)(vt + ((size_t)(b * NH + h) * DK + dd) * SEQ + s0 + sl2) = val;
    }
}

// ---------------- Flash attention, 32 queries/wave, fragment-ordered LDS K/V --------
__global__ __launch_bounds__(256, 2) void attn_kernel(const __bf16* __restrict__ qkv,
                                                      const __bf16* __restrict__ vt,
                                                      __bf16* __restrict__ ctx) {
    __shared__ __bf16 Klds[8192];        // 16 blocks x 1024B, block (f,half)=f*2+half
    __shared__ __bf16 Vlds[8192];        // 16 blocks x 1024B, block (c,ti)=c*4+ti
    __shared__ __bf16 Plds[4][32][136];  // [wave][query 32][128 keys + 8 pad]
    int b = blockIdx.z, h = blockIdx.y;
    int wave = threadIdx.x >> 6, lane = threadIdx.x & 63;
    int q0 = blockIdx.x * 128 + wave * 32;
    int fr = lane & 15, quad = lane >> 4;
    const float sc2 = 0.18033688011112042f;   // (1/sqrt(64)) * log2(e)

    const __bf16* qp0 = qkv + (size_t)(b * SEQ + q0 + fr) * QKVS + h * DK + quad * 8;
    const __bf16* qp1 = qp0 + (size_t)16 * QKVS;
    bf16x8 qA0 = *(const bf16x8*)qp0, qB0 = *(const bf16x8*)(qp0 + 32);
    bf16x8 qA1 = *(const bf16x8*)qp1, qB1 = *(const bf16x8*)(qp1 + 32);

    const __bf16* kg = qkv + (size_t)b * SEQ * QKVS + 1024 + h * DK;  // + key*QKVS + d
    const __bf16* vg = vt + (size_t)(b * NH + h) * DK * SEQ;          // + d*SEQ + key

    floatx4 o[8] = {};   // [hh*4+ti]: row=query hh*16+quad*4+r, col=d ti*16+fr
    float m0q = -1e30f, l0q = 0.f, m1q = -1e30f, l1q = 0.f;

    auto stage_tile = [&](int k0) {
#pragma unroll
        for (int p = 0; p < 4; ++p) {
            int bid = wave * 4 + p;
            int f = bid >> 1, half = bid & 1;
            __builtin_amdgcn_global_load_lds(
                (gbl_void_t*)(kg + (size_t)(k0 + f * 16 + fr) * QKVS + quad * 8 + half * 32),
                (lds_void_t*)&Klds[bid * 512], 16, 0, 0);
            int c = bid >> 2, ti = bid & 3;
            __builtin_amdgcn_global_load_lds(
                (gbl_void_t*)(vg + (size_t)(ti * 16 + fr) * SEQ + k0 + c * 32 + quad * 8),
                (lds_void_t*)&Vlds[bid * 512], 16, 0, 0);
        }
    };

    stage_tile(0);
    __syncthreads();   // drains vmcnt -> tile 0 in LDS

    for (int k0 = 0; k0 < SEQ; k0 += 128) {
        const __bf16* Kb = Klds + lane * 8;
        const __bf16* Vb = Vlds + lane * 8;
        bf16x8 kA[8], kB[8];
#pragma unroll
        for (int f = 0; f < 8; ++f) {
            kA[f] = *(const bf16x8*)(Kb + (f * 2 + 0) * 512);
            kB[f] = *(const bf16x8*)(Kb + (f * 2 + 1) * 512);
        }

        // ---- QK^T half 0 ----
        floatx4 s[8];
#pragma unroll
        for (int f = 0; f < 8; ++f) {
            floatx4 z = {0.f, 0.f, 0.f, 0.f};
            z = __builtin_amdgcn_mfma_f32_16x16x32_bf16(kA[f], qA0, z, 0, 0, 0);
            s[f] = __builtin_amdgcn_mfma_f32_16x16x32_bf16(kB[f], qB0, z, 0, 0, 0);
        }
        // ---- softmax half 0 ----
        {
            float fm[8];
#pragma unroll
            for (int f = 0; f < 8; ++f)
                fm[f] = fmaxf(fmaxf(s[f][0], s[f][1]), fmaxf(s[f][2], s[f][3]));
            float mx = fmaxf(fmaxf(fmaxf(fm[0], fm[1]), fmaxf(fm[2], fm[3])),
                             fmaxf(fmaxf(fm[4], fm[5]), fmaxf(fm[6], fm[7])));
            float mx2 = mx * sc2;
            mx2 = fmaxf(mx2, __shfl_xor(mx2, 16));
            mx2 = fmaxf(mx2, __shfl_xor(mx2, 32));
            float mn = fmaxf(m0q, mx2);
            float alpha = EXP2(m0q - mn);
            m0q = mn;
            float r0 = 0.f, r1 = 0.f, r2 = 0.f, r3 = 0.f;
#pragma unroll
            for (int f = 0; f < 8; ++f) {
                bf16x4 pk;
                float p0 = EXP2(fmaf(s[f][0], sc2, -mn));
                float p1 = EXP2(fmaf(s[f][1], sc2, -mn));
                float p2 = EXP2(fmaf(s[f][2], sc2, -mn));
                float p3 = EXP2(fmaf(s[f][3], sc2, -mn));
                r0 += p0; r1 += p1; r2 += p2; r3 += p3;
                pk[0] = (__bf16)p0; pk[1] = (__bf16)p1; pk[2] = (__bf16)p2; pk[3] = (__bf16)p3;
                *(bf16x4*)&Plds[wave][fr][f * 16 + quad * 4] = pk;
            }
            float rs = (r0 + r1) + (r2 + r3);
            rs += __shfl_xor(rs, 16);
            rs += __shfl_xor(rs, 32);
            l0q = l0q * alpha + rs;
            float aB[4];
#pragma unroll
            for (int r = 0; r < 4; ++r) aB[r] = __shfl(alpha, quad * 4 + r);
#pragma unroll
            for (int ti = 0; ti < 4; ++ti)
#pragma unroll
                for (int r = 0; r < 4; ++r) o[ti][r] *= aB[r];
        }

        // ---- QK^T half 1 ----
        floatx4 s1[8];
#pragma unroll
        for (int f = 0; f < 8; ++f) {
            floatx4 z = {0.f, 0.f, 0.f, 0.f};
            z = __builtin_amdgcn_mfma_f32_16x16x32_bf16(kA[f], qA1, z, 0, 0, 0);
            s1[f] = __builtin_amdgcn_mfma_f32_16x16x32_bf16(kB[f], qB1, z, 0, 0, 0);
        }

        // ---- V fragment reads (K regs free) ----
        bf16x8 vf[4][4];
#pragma unroll
        for (int c = 0; c < 4; ++c)
#pragma unroll
            for (int ti = 0; ti < 4; ++ti)
                vf[c][ti] = *(const bf16x8*)(Vb + (c * 4 + ti) * 512);

        __syncthreads();   // all waves done reading K/V LDS
        if (k0 + 128 < SEQ) stage_tile(k0 + 128);   // loads fly under softmax h1 + PV

        // ---- softmax half 1 ----
        {
            float fm[8];
#pragma unroll
            for (int f = 0; f < 8; ++f)
                fm[f] = fmaxf(fmaxf(s1[f][0], s1[f][1]), fmaxf(s1[f][2], s1[f][3]));
            float mx = fmaxf(fmaxf(fmaxf(fm[0], fm[1]), fmaxf(fm[2], fm[3])),
                             fmaxf(fmaxf(fm[4], fm[5]), fmaxf(fm[6], fm[7])));
            float mx2 = mx * sc2;
            mx2 = fmaxf(mx2, __shfl_xor(mx2, 16));
            mx2 = fmaxf(mx2, __shfl_xor(mx2, 32));
            float mn = fmaxf(m1q, mx2);
            float alpha = EXP2(m1q - mn);
            m1q = mn;
            float r0 = 0.f, r1 = 0.f, r2 = 0.f, r3 = 0.f;
#pragma unroll
            for (int f = 0; f < 8; ++f) {
                bf16x4 pk;
                float p0 = EXP2(fmaf(s1[f][0], sc2, -mn));
                float p1 = EXP2(fmaf(s1[f][1], sc2, -mn));
                float p2 = EXP2(fmaf(s1[f][2], sc2, -mn));
                float p3 = EXP2(fmaf(s1[f][3], sc2, -mn));
                r0 += p0; r1 += p1; r2 += p2; r3 += p3;
                pk[0] = (__bf16)p0; pk[1] = (__bf16)p1; pk[2] = (__bf16)p2; pk[3] = (__bf16)p3;
                *(bf16x4*)&Plds[wave][16 + fr][f * 16 + quad * 4] = pk;
            }
            float rs = (r0 + r1) + (r2 + r3);
            rs += __shfl_xor(rs, 16);
            rs += __shfl_xor(rs, 32);
            l1q = l1q * alpha + rs;
            float aB[4];
#pragma unroll
            for (int r = 0; r < 4; ++r) aB[r] = __shfl(alpha, quad * 4 + r);
#pragma unroll
            for (int ti = 0; ti < 4; ++ti)
#pragma unroll
                for (int r = 0; r < 4; ++r) o[4 + ti][r] *= aB[r];
        }
        __threadfence_block();   // order wave-private Plds writes -> cross-lane reads

        // ---- PV both halves ----
        bf16x8 pa0[4], pa1[4];
#pragma unroll
        for (int c = 0; c < 4; ++c) {
            pa0[c] = *(const bf16x8*)&Plds[wave][fr][c * 32 + quad * 8];
            pa1[c] = *(const bf16x8*)&Plds[wave][16 + fr][c * 32 + quad * 8];
        }
#pragma unroll
        for (int c = 0; c < 4; ++c)
#pragma unroll
            for (int ti = 0; ti < 4; ++ti) {
                o[ti]     = __builtin_amdgcn_mfma_f32_16x16x32_bf16(pa0[c], vf[c][ti], o[ti], 0, 0, 0);
                o[4 + ti] = __builtin_amdgcn_mfma_f32_16x16x32_bf16(pa1[c], vf[c][ti], o[4 + ti], 0, 0, 0);
            }
        __threadfence_block();   // P reads done before next iteration's writes

        __syncthreads();   // drains vmcnt -> staged tile t+1 ready in LDS
    }
    float lB0[4], lB1[4];
#pragma unroll
    for (int r = 0; r < 4; ++r) {
        lB0[r] = __shfl(l0q, quad * 4 + r);
        lB1[r] = __shfl(l1q, quad * 4 + r);
    }
#pragma unroll
    for (int ti = 0; ti < 4; ++ti)
#pragma unroll
        for (int r = 0; r < 4; ++r) {
            ctx[(size_t)(b * SEQ + q0 + quad * 4 + r) * D_MODEL + h * DK + ti * 16 + fr] =
                (__bf16)(o[ti][r] / lB0[r]);
            ctx[(size_t)(b * SEQ + q0 + 16 + quad * 4 + r) * D_MODEL + h * DK + ti * 16 + fr] =
                (__bf16)(o[4 + ti][r] / lB1[r]);
        }
}

// -----------------------------------------------------------------------------------
// Workspace 72 MiB:
//   [0,6M):   wqkvB    [6,8M): woB    [8,16M): w1B    [16,24M): w2B
//   [24,40M): h1 -> x1 fp32 trunk
//   [40,64M): qkv      [64,72M): vt
//   AO split-K partials:  [40,56M) + [56,72M)  (qkv/vt dead after attn)
//   ffh = [40,72M) after AO reduce_ln
//   FF2 split-K partials: [0,16M) (wqkvB/woB/w1B dead) + d_out (h2 dead)
//   d_out:    ctx -> h2 -> FF2 partial1 -> final out
extern "C" void kernel_launch(void* const* d_in, const int* in_sizes, int n_in,
                              void* d_out, int out_size, void* d_ws, size_t ws_size,
                              hipStream_t stream) {
    const float* x   = (const float*)d_in[0];
    const float* wq  = (const float*)d_in[1];
    const float* bq  = (const float*)d_in[2];
    const float* wk  = (const float*)d_in[3];
    const float* bk  = (const float*)d_in[4];
    const float* wv  = (const float*)d_in[5];
    const float* bv  = (const float*)d_in[6];
    const float* wo  = (const float*)d_in[7];
    const float* bo  = (const float*)d_in[8];
    const float* w1  = (const float*)d_in[9];
    const float* b1  = (const float*)d_in[10];
    const float* w2  = (const float*)d_in[11];
    const float* b2  = (const float*)d_in[12];
    const float* g1  = (const float*)d_in[13];
    const float* be1 = (const float*)d_in[14];
    const float* g2  = (const float*)d_in[15];
    const float* be2 = (const float*)d_in[16];
    float* out = (float*)d_out;

    char* ws = (char*)d_ws;
    const size_t MB = 1024 * 1024;
    __bf16* wqkvB = (__bf16*)(ws);                 // [0,6M)
    __bf16* woB   = (__bf16*)(ws + 6 * MB);
    __bf16* w1B   = (__bf16*)(ws + 8 * MB);
    __bf16* w2B   = (__bf16*)(ws + 16 * MB);
    __bf16* h1    = (__bf16*)(ws + 24 * MB);       // dead after qkv-gemm
    float*  x1    = (float*)(ws + 24 * MB);        // fp32 trunk [24,40M)
    __bf16* qkv   = (__bf16*)(ws + 40 * MB);       // [40,64M)
    __bf16* vt    = (__bf16*)(ws + 64 * MB);       // [64,72M)
    __bf16* ffh   = (__bf16*)(ws + 40 * MB);       // [40,72M) after qkv+vt die
    float*  pA0   = (float*)(ws + 40 * MB);        // AO partial z=0
    float*  pA1   = (float*)(ws + 56 * MB);        // AO partial z=1
    float*  pF0   = (float*)(ws);                  // FF2 partial z=0 [0,16M)
    __bf16* ctx   = (__bf16*)d_out;                // d_out scratch [0,8M)
    __bf16* h2    = (__bf16*)d_out;                // d_out scratch (after ctx dies)

    dim3 gQKV(QKVS / 128, NTOK / 256);       // (24, 16) = 384 blocks, 256-row tile
    dim3 gDz(D_MODEL / 128, NTOK / 128, 2);  // (8, 32, 2) = 512 blocks, split-K=2
    dim3 gF(DFF / 128, NTOK / 256);          // (32, 16) = 512 blocks, 256-row tile
    dim3 gTr(SEQ / 64, NH, BATCH);           // (32, 16, 2) transpose_v
    dim3 gAttn(SEQ / 128, NH, BATCH);        // (16, 16, 2) = 512 blocks, 2/CU
    int gRed = NTOK * D_MODEL / (256 * 4);   // 4096 blocks

    // 0. all weight casts in one launch (6144 blocks)
    cast_all<<<6144, 256, 0, stream>>>(wq, wk, wv, wo, w1, w2, wqkvB, woB, w1B, w2B);
    // 1. h1 = LN(x, g1, be1)
    ln_kernel<<<NTOK, 64, 0, stream>>>(x, g1, be1, h1);
    // 2. qkv = h1 @ [wq;wk;wv]^T + [bq;bk;bv]   (fused, N=3072; 256-row tile)
    gemm256<__bf16, false, true><<<gQKV, 512, 0, stream>>>(h1, wqkvB, bq, bk, bv, qkv, NTOK, QKVS, D_MODEL);
    // 3. vt = transpose(v) per head
    transpose_v<<<gTr, 256, 0, stream>>>(qkv, vt);
    // 4. ctx = softmax(q k^T / sqrt(dk)) v   (writes d_out)
    attn_kernel<<<gAttn, 256, 0, stream>>>(qkv, vt, ctx);
    // 5. AO split-K=2: partials over dead qkv/vt
    gemm_bt<float, false, false, 2><<<gDz, 256, 0, stream>>>(ctx, woB, nullptr, nullptr, nullptr, nullptr, pA0, pA1, NTOK, D_MODEL, D_MODEL);
    // 6. x1 = pA0+pA1+x+bo;  h2 = LN(x1, g2, be2)   (fused reduce+LN; h2 overwrites ctx)
    reduce_ln<<<NTOK, 64, 0, stream>>>(pA0, pA1, x, bo, g2, be2, x1, h2);
    // 7. ffh = gelu(h2 @ w1^T + b1)   (256-row tile, 512 blocks)
    gemm256<__bf16, true, false><<<gF, 512, 0, stream>>>(h2, w1B, b1, b1, b1, ffh, NTOK, DFF, D_MODEL);
    // 8. out = x1 + ffh @ w2^T + b2   (split-K=2: p0=[0,16M), p1=d_out, reduce in place)
    gemm_bt<float, false, false, 2><<<gDz, 256, 0, stream>>>(ffh, w2B, nullptr, nullptr, nullptr, nullptr, pF0, (float*)d_out, NTOK, D_MODEL, DFF);
    reduce_k2<<<gRed, 256, 0, stream>>>(pF0, (float*)d_out, x1, b2, out);
}